// Round 5
// baseline (201.817 us; speedup 1.0000x reference)
//
#include <hip/hip_runtime.h>
#include <math.h>

// EdgeSelector: B=32, N=64, D=64, H=4, E=256, HD=64
// out = [em (32,64,4,64) | sampled (32,64,4,64)] f32
// ws (floats): xn[131072] | T1s[1572864] (frag-swizzled) | T2[1572864] |
//              bf16: Wb[768*128] w1b[64*64]

typedef __attribute__((ext_vector_type(8))) short short8;   // 8 bf16 = 4 VGPR
typedef __attribute__((ext_vector_type(4))) float f32x4;

__device__ __forceinline__ short f2b(float f) {  // RNE f32->bf16
  unsigned u = __builtin_bit_cast(unsigned, f);
  unsigned r = (u + 0x7FFFu + ((u >> 16) & 1u)) >> 16;
  return (short)r;
}

#define WCS 136  // Wc row stride in shorts (272 B)
#define TS  72   // q/k/vT/A2/w row stride in shorts (144 B)

// LDS: WC (Wc, then attn-w) | RA (Q then A2) | RB (K) | RC (VT) | F (448 f32)
#define OFF_WC 0
#define OFF_RA 17408
#define OFF_RB 26624
#define OFF_RC 35840
#define OFF_F  45056
#define LDS_BYTES 46848
// sF: [0,192) T2h | [192,256) mask | [256,320) logits | [320,384) b1 | [384,448) w2

// ---------------- K1: xn = LN(x)*g+b, zeroed where row has no neighbors ----
__global__ __launch_bounds__(256) void k_node_ln(
    const float* __restrict__ x, const int* __restrict__ mask,
    const float* __restrict__ g, const float* __restrict__ bb,
    float* __restrict__ xn) {
  int tid = threadIdx.x;
  int row = blockIdx.x * 4 + (tid >> 6);
  int lane = tid & 63;
  float v = x[row * 64 + lane];
  float s = v;
#pragma unroll
  for (int m = 1; m < 64; m <<= 1) s += __shfl_xor(s, m, 64);
  float mean = s * (1.0f / 64.0f);
  float dv = v - mean;
  float s2 = dv * dv;
#pragma unroll
  for (int m = 1; m < 64; m <<= 1) s2 += __shfl_xor(s2, m, 64);
  float rstd = rsqrtf(s2 * (1.0f / 64.0f) + 1e-5f);
  float msum = (float)mask[row * 64 + lane];
#pragma unroll
  for (int m = 1; m < 64; m <<= 1) msum += __shfl_xor(msum, m, 64);
  float ped = (msum > 0.0f) ? 1.0f : 0.0f;
  xn[row * 64 + lane] = (dv * rstd * g[lane] + bb[lane]) * ped;
}

// ---- K2: T1s (frag-swizzled) = W[f,0:64]·xn[r]; T2[r,f] = W[f,64:128]·xn[r]+bias
// T1s layout: [((((b*3+p)*4+h)*4 + wave)*64 + lane)*16 + nt*4 + r]
// where (m = wave*16 + lh*4 + r, lane = lh*16 + lr, dcol = nt*16 + lr, f = p*256+h*64+dcol)
__global__ __launch_bounds__(256) void k_t12(
    const float* __restrict__ xn, const float* __restrict__ W,
    const float* __restrict__ bias, float* __restrict__ T1s, float* __restrict__ T2) {
  __shared__ __align__(16) float sx[8 * 64];
  int tid = threadIdx.x;
  int r0 = blockIdx.x * 8;
#pragma unroll
  for (int u = 0; u < 2; ++u) {
    int idx = tid + 256 * u;
    sx[idx] = xn[r0 * 64 + idx];
  }
  __syncthreads();
#pragma unroll
  for (int ff = 0; ff < 3; ++ff) {
    int f = tid + 256 * ff;
    float acc1[8], acc2[8];
#pragma unroll
    for (int r = 0; r < 8; ++r) { acc1[r] = 0.f; acc2[r] = 0.f; }
    for (int e4 = 0; e4 < 64; e4 += 4) {
      float4 wa = *(const float4*)&W[f * 256 + e4];
      float4 wb = *(const float4*)&W[f * 256 + 64 + e4];
#pragma unroll
      for (int r = 0; r < 8; ++r) {
        float4 xv = *(const float4*)&sx[r * 64 + e4];
        acc1[r] += wa.x * xv.x + wa.y * xv.y + wa.z * xv.z + wa.w * xv.w;
        acc2[r] += wb.x * xv.x + wb.y * xv.y + wb.z * xv.z + wb.w * xv.w;
      }
    }
    float bv = bias[f];
    int p = f >> 8, hh = (f >> 6) & 3, nt = (f >> 4) & 3, lr = f & 15;
#pragma unroll
    for (int r = 0; r < 8; ++r) {
      int m = r0 + r;
      int bb2 = m >> 6, mm = m & 63;
      int w = mm >> 4, lh = (mm >> 2) & 3, rr = mm & 3;
      T1s[(size_t)((((bb2 * 3 + p) * 4 + hh) * 4 + w) * 64 + lh * 16 + lr) * 16 +
          nt * 4 + rr] = acc1[r];
      T2[m * 768 + f] = acc2[r] + bv;
    }
  }
}

// ---------------- K_wb: bf16 copies of W[:,128:256] and w1 ----------------
__global__ __launch_bounds__(256) void k_wb(const float* __restrict__ W,
                                            const float* __restrict__ w1,
                                            short* __restrict__ Wb,
                                            short* __restrict__ w1b) {
  int idx = blockIdx.x * 256 + threadIdx.x;
  if (idx < 12288) {  // 768 rows x 16 granules of 8
    int f = idx >> 4, gi = idx & 15;
    const float* src = &W[(size_t)f * 256 + 128 + gi * 8];
    short8 o;
#pragma unroll
    for (int i = 0; i < 8; ++i) o[i] = f2b(src[i]);
    *(short8*)&Wb[f * 128 + gi * 8] = o;
  } else if (idx < 12288 + 512) {  // 64 x 8 granules
    int g2 = idx - 12288;
    int f = g2 >> 3, gi = g2 & 7;
    const float* src = &w1[f * 64 + gi * 8];
    short8 o;
#pragma unroll
    for (int i = 0; i < 8; ++i) o[i] = f2b(src[i]);
    *(short8*)&w1b[f * 64 + gi * 8] = o;
  }
}

// ---------------- K3: fused per-(b,t,h) ----------------
__global__ __launch_bounds__(256, 3) void k_main(
    const float* __restrict__ A, const int* __restrict__ mask,
    const float* __restrict__ gu, const float* __restrict__ leg,
    const float* __restrict__ leb, const float* __restrict__ b1g,
    const float* __restrict__ w2g, const float* __restrict__ b2g,
    const float* __restrict__ T1s, const float* __restrict__ T2,
    const short* __restrict__ Wb, const short* __restrict__ w1b,
    float* __restrict__ out) {
  __shared__ __align__(16) unsigned char smem[LDS_BYTES];
  short* sWc = (short*)(smem + OFF_WC);  // Wc staging; attn-w after proj
  short* sWt = (short*)(smem + OFF_WC);
  short* sQ  = (short*)(smem + OFF_RA);  // Q, then A2
  short* sA2 = (short*)(smem + OFF_RA);
  short* sK  = (short*)(smem + OFF_RB);
  short* sVT = (short*)(smem + OFF_RC);
  float* sF  = (float*)(smem + OFF_F);

  int tid = threadIdx.x;
  int bid0 = blockIdx.x;
  int wg = (bid0 & 7) * 1024 + (bid0 >> 3);  // XCD swizzle (8192 % 8 == 0)
  int h = wg & 3, t = (wg >> 2) & 63, b = wg >> 8;
  int bt = b * 64 + t;
  int wave = tid >> 6, lane = tid & 63, lr = lane & 15, lh = lane >> 4;

  // ---- issue A-row loads first (longest latency) ----
  int m0 = wave * 16 + lr;
  const float* Ar = A + ((size_t)((b * 64 + m0) * 64 + t)) * 128;
  float4 a4[8];
#pragma unroll
  for (int ks = 0; ks < 4; ++ks) {
    a4[2 * ks]     = *(const float4*)&Ar[ks * 32 + lh * 8];
    a4[2 * ks + 1] = *(const float4*)&Ar[ks * 32 + lh * 8 + 4];
  }

  // ---- T1 fragment preloads: all 3 parts, coalesced float4 ----
  float4 t1f[3][4];
#pragma unroll
  for (int p = 0; p < 3; ++p)
#pragma unroll
    for (int nt = 0; nt < 4; ++nt)
      t1f[p][nt] = *(const float4*)&T1s[
          (size_t)((((b * 3 + p) * 4 + h) * 4 + wave) * 64 + lane) * 16 + nt * 4];

  // ---- stage Wc for p=0 (before first barrier) ----
#pragma unroll
  for (int u = 0; u < 4; ++u) {
    int idx = tid + 256 * u;
    int dR = idx >> 4, gi = idx & 15;
    *(short8*)&sWc[dR * WCS + gi * 8] =
        *(const short8*)&Wb[(size_t)(h * 64 + dR) * 128 + gi * 8];
  }

  // ---- stage small constants into sF ----
  if (tid < 192) sF[tid] = T2[bt * 768 + (tid >> 6) * 256 + h * 64 + (tid & 63)];
  else sF[192 + tid - 192] = (float)mask[bt * 64 + tid - 192];
  if (tid < 64) sF[320 + tid] = b1g[tid];
  else if (tid < 128) sF[384 + tid - 64] = w2g[tid - 64];

  // ---- An LN fully in registers (uses a4) ----
  short8 af[4];
  {
    float s = 0.f, s2 = 0.f;
#pragma unroll
    for (int q = 0; q < 8; ++q) {
      float4 u0 = a4[q];
      s += u0.x + u0.y + u0.z + u0.w;
      s2 += u0.x * u0.x + u0.y * u0.y + u0.z * u0.z + u0.w * u0.w;
    }
    s += __shfl_xor(s, 16, 64);  s += __shfl_xor(s, 32, 64);
    s2 += __shfl_xor(s2, 16, 64); s2 += __shfl_xor(s2, 32, 64);
    float mean = s * (1.0f / 128.0f);
    float var = s2 * (1.0f / 128.0f) - mean * mean;
    float rstd = rsqrtf(var + 1e-5f);
    float mv = (float)mask[bt * 64 + m0];
#pragma unroll
    for (int ks = 0; ks < 4; ++ks) {
      float4 g0 = *(const float4*)&leg[ks * 32 + lh * 8];
      float4 g1 = *(const float4*)&leg[ks * 32 + lh * 8 + 4];
      float4 c0 = *(const float4*)&leb[ks * 32 + lh * 8];
      float4 c1 = *(const float4*)&leb[ks * 32 + lh * 8 + 4];
      float gg[8] = {g0.x, g0.y, g0.z, g0.w, g1.x, g1.y, g1.z, g1.w};
      float cc[8] = {c0.x, c0.y, c0.z, c0.w, c1.x, c1.y, c1.z, c1.w};
      float4 u0 = a4[2 * ks], u1 = a4[2 * ks + 1];
      float vv[8] = {u0.x, u0.y, u0.z, u0.w, u1.x, u1.y, u1.z, u1.w};
#pragma unroll
      for (int i = 0; i < 8; ++i)
        af[ks][i] = f2b(((vv[i] - mean) * rstd * gg[i] + cc[i]) * mv);
    }
  }
  __syncthreads();  // #1: sF + Wc(p=0) visible

  // ---- projection p=0(q),1(k),2(v): acc initialized from T1 frags ----
#pragma unroll
  for (int p = 0; p < 3; ++p) {
    f32x4 acc[4];
#pragma unroll
    for (int nt = 0; nt < 4; ++nt) {
      float4 tv = t1f[p][nt];
      acc[nt][0] = tv.x; acc[nt][1] = tv.y; acc[nt][2] = tv.z; acc[nt][3] = tv.w;
    }
    __builtin_amdgcn_s_setprio(1);
#pragma unroll
    for (int ks = 0; ks < 4; ++ks)
#pragma unroll
      for (int nt = 0; nt < 4; ++nt) {
        short8 bf = *(const short8*)&sWc[(nt * 16 + lr) * WCS + ks * 32 + lh * 8];
        acc[nt] = __builtin_amdgcn_mfma_f32_16x16x32_bf16(af[ks], bf, acc[nt], 0, 0, 0);
      }
    __builtin_amdgcn_s_setprio(0);
#pragma unroll
    for (int nt = 0; nt < 4; ++nt)
#pragma unroll
      for (int r = 0; r < 4; ++r) {
        int m = wave * 16 + lh * 4 + r;
        int dcol = nt * 16 + lr;
        float val = acc[nt][r] + sF[p * 64 + dcol];
        if (p == 0)      sQ[m * TS + dcol] = f2b(val * 0.125f);  // * hd^-0.5
        else if (p == 1) sK[m * TS + dcol] = f2b(val);
        else             sVT[dcol * TS + m] = f2b(val);
      }
    __syncthreads();  // Wc reads + epilogue done
    if (p < 2) {
      int Fb = (p + 1) * 256 + h * 64;
#pragma unroll
      for (int u = 0; u < 4; ++u) {
        int idx = tid + 256 * u;
        int dR = idx >> 4, gi = idx & 15;
        *(short8*)&sWc[dR * WCS + gi * 8] =
            *(const short8*)&Wb[(size_t)(Fb + dR) * 128 + gi * 8];
      }
      __syncthreads();  // next Wc visible
    }
  }

  // ---- scores + masked softmax (exact ref algebra) ----
  float wv[4][4];
  {
    f32x4 sc[4] = {};
    __builtin_amdgcn_s_setprio(1);
#pragma unroll
    for (int ks = 0; ks < 2; ++ks) {
      short8 qf = *(const short8*)&sQ[(wave * 16 + lr) * TS + ks * 32 + lh * 8];
#pragma unroll
      for (int nt = 0; nt < 4; ++nt) {
        short8 kf = *(const short8*)&sK[(nt * 16 + lr) * TS + ks * 32 + lh * 8];
        sc[nt] = __builtin_amdgcn_mfma_f32_16x16x32_bf16(qf, kf, sc[nt], 0, 0, 0);
      }
    }
    __builtin_amdgcn_s_setprio(0);
    float mk[4];
#pragma unroll
    for (int nt = 0; nt < 4; ++nt) mk[nt] = sF[192 + nt * 16 + lr];
#pragma unroll
    for (int r = 0; r < 4; ++r) {
      int j = wave * 16 + lh * 4 + r;
      float mj = sF[192 + j];
      float mx = fmaxf(fmaxf(sc[0][r], sc[1][r]), fmaxf(sc[2][r], sc[3][r]));
#pragma unroll
      for (int mm = 1; mm < 16; mm <<= 1) mx = fmaxf(mx, __shfl_xor(mx, mm, 64));
      float pv[4], Zf = 0.f, S = 0.f;
#pragma unroll
      for (int nt = 0; nt < 4; ++nt) {
        pv[nt] = expf(sc[nt][r] - mx);
        Zf += pv[nt];
        S += pv[nt] * mk[nt];
      }
#pragma unroll
      for (int mm = 1; mm < 16; mm <<= 1) {
        Zf += __shfl_xor(Zf, mm, 64);
        S += __shfl_xor(S, mm, 64);
      }
      // w = softmax*m3 renormed == p*mk*mj / (mj*S + 1e-10*Z)
      float inv = mj / (S + 1e-10f * Zf);
#pragma unroll
      for (int nt = 0; nt < 4; ++nt) wv[r][nt] = pv[nt] * mk[nt] * inv;
    }
  }
  // ---- transpose w via LDS (Wc region, dead): same-wave rows, no barrier ----
#pragma unroll
  for (int r = 0; r < 4; ++r)
#pragma unroll
    for (int nt = 0; nt < 4; ++nt)
      sWt[(wave * 16 + lh * 4 + r) * TS + nt * 16 + lr] = f2b(wv[r][nt]);

  // ---- A2[j,d] = sum_k w[j,k]*v[k,d]; write into R_A (Q dead, same-wave) ----
  {
    f32x4 a2[4] = {};
    __builtin_amdgcn_s_setprio(1);
#pragma unroll
    for (int ks = 0; ks < 2; ++ks) {
      short8 wf = *(const short8*)&sWt[(wave * 16 + lr) * TS + ks * 32 + lh * 8];
#pragma unroll
      for (int nt = 0; nt < 4; ++nt) {
        short8 vf = *(const short8*)&sVT[(nt * 16 + lr) * TS + ks * 32 + lh * 8];
        a2[nt] = __builtin_amdgcn_mfma_f32_16x16x32_bf16(wf, vf, a2[nt], 0, 0, 0);
      }
    }
    __builtin_amdgcn_s_setprio(0);
#pragma unroll
    for (int nt = 0; nt < 4; ++nt)
#pragma unroll
      for (int r = 0; r < 4; ++r)
        sA2[(wave * 16 + lh * 4 + r) * TS + nt * 16 + lr] = f2b(a2[nt][r]);
  }

  // ---- hmid = relu(A2·w1^T + b1); logits[j] = hmid·w2 (w1 frags from global) ----
  {
    f32x4 hm[4] = {};
    __builtin_amdgcn_s_setprio(1);
#pragma unroll
    for (int ks = 0; ks < 2; ++ks) {
      short8 a2f = *(const short8*)&sA2[(wave * 16 + lr) * TS + ks * 32 + lh * 8];
#pragma unroll
      for (int nt = 0; nt < 4; ++nt) {
        short8 wf = *(const short8*)&w1b[(nt * 16 + lr) * 64 + ks * 32 + lh * 8];
        hm[nt] = __builtin_amdgcn_mfma_f32_16x16x32_bf16(a2f, wf, hm[nt], 0, 0, 0);
      }
    }
    __builtin_amdgcn_s_setprio(0);
    float b1v[4], w2v[4];
#pragma unroll
    for (int nt = 0; nt < 4; ++nt) {
      b1v[nt] = sF[320 + nt * 16 + lr];
      w2v[nt] = sF[384 + nt * 16 + lr];
    }
#pragma unroll
    for (int r = 0; r < 4; ++r) {
      float pp = 0.f;
#pragma unroll
      for (int nt = 0; nt < 4; ++nt)
        pp += fmaxf(hm[nt][r] + b1v[nt], 0.f) * w2v[nt];
#pragma unroll
      for (int mm = 1; mm < 16; mm <<= 1) pp += __shfl_xor(pp, mm, 64);
      if (lr == 0) sF[256 + wave * 16 + lh * 4 + r] = pp;
    }
  }
  __syncthreads();  // logits ready

  // ---- em + gumbel + sampled (wave 0, lane j) ----
  if (tid < 64) {
    int j = tid;
    float l = sF[256 + j] + b2g[0];
    float mjv = sF[192 + j];
    float mx = l;
#pragma unroll
    for (int mm = 1; mm < 64; mm <<= 1) mx = fmaxf(mx, __shfl_xor(mx, mm, 64));
    float pv = expf(l - mx);
    float Z = pv;
#pragma unroll
    for (int mm = 1; mm < 64; mm <<= 1) Z += __shfl_xor(Z, mm, 64);
    float ep = (pv / Z) * mjv;
    float S = ep;
#pragma unroll
    for (int mm = 1; mm < 64; mm <<= 1) S += __shfl_xor(S, mm, 64);
    float em = ep / (S + 1e-10f);
    float u = gu[((size_t)bt * 4 + h) * 64 + j];
    float gg = -logf(-logf(u + 1e-10f) + 1e-10f);
    float l2 = logf(em + 1e-10f) + gg;  // TAU = 1
    float mx2 = l2;
#pragma unroll
    for (int mm = 1; mm < 64; mm <<= 1) mx2 = fmaxf(mx2, __shfl_xor(mx2, mm, 64));
    float p2 = expf(l2 - mx2);
    float Z2 = p2;
#pragma unroll
    for (int mm = 1; mm < 64; mm <<= 1) Z2 += __shfl_xor(Z2, mm, 64);
    float smp = p2 / Z2;
    size_t o = ((size_t)bt * 4 + h) * 64 + j;
    out[o] = em;
    out[524288 + o] = smp;
  }
}

extern "C" void kernel_launch(void* const* d_in, const int* in_sizes, int n_in,
                              void* d_out, int out_size, void* d_ws, size_t ws_size,
                              hipStream_t stream) {
  const float* x    = (const float*)d_in[0];
  const float* A    = (const float*)d_in[1];
  const int*   mask = (const int*)d_in[2];
  const float* gu   = (const float*)d_in[3];
  const float* lng  = (const float*)d_in[4];
  const float* lnb  = (const float*)d_in[5];
  const float* leg  = (const float*)d_in[6];
  const float* leb  = (const float*)d_in[7];
  const float* W    = (const float*)d_in[8];
  const float* bias = (const float*)d_in[9];
  const float* w1   = (const float*)d_in[10];
  const float* b1   = (const float*)d_in[11];
  const float* w2   = (const float*)d_in[12];
  const float* b2   = (const float*)d_in[13];
  float* out = (float*)d_out;
  float* ws  = (float*)d_ws;

  float* xn  = ws;                       // 131072 floats
  float* T1s = xn + 131072;              // 1572864 floats (frag-swizzled)
  float* T2  = T1s + 1572864;            // 1572864 floats
  short* Wb  = (short*)(T2 + 1572864);   // 98304 shorts
  short* w1b = Wb + 98304;               // 4096 shorts

  k_wb<<<50, 256, 0, stream>>>(W, w1, Wb, w1b);
  k_node_ln<<<512, 256, 0, stream>>>(x, mask, lng, lnb, xn);
  k_t12<<<256, 256, 0, stream>>>(xn, W, bias, T1s, T2);
  k_main<<<8192, 256, 0, stream>>>(A, mask, gu, leg, leb, b1, w2, b2,
                                   T1s, T2, Wb, w1b, out);
}

// Round 6
// 166.085 us; speedup vs baseline: 1.2151x; 1.2151x over previous
//
#include <hip/hip_runtime.h>
#include <math.h>

// EdgeSelector: B=32, N=64, D=64, H=4, E=256, HD=64
// out = [em (32,64,4,64) | sampled (32,64,4,64)] f32
// ws (floats): xn[131072] | T1s[1572864] (frag-swizzled) | T2[1572864] |
//              bf16: Wb[768*128] w1b[64*64]

typedef __attribute__((ext_vector_type(8))) short short8;   // 8 bf16 = 4 VGPR
typedef __attribute__((ext_vector_type(4))) float f32x4;

__device__ __forceinline__ short f2b(float f) {  // RNE f32->bf16
  unsigned u = __builtin_bit_cast(unsigned, f);
  unsigned r = (u + 0x7FFFu + ((u >> 16) & 1u)) >> 16;
  return (short)r;
}

#define WCS 136  // Wc row stride in shorts (272 B)
#define TS  72   // q/k/vT/A2/w row stride in shorts (144 B, 16B-aligned)

// LDS: WC region [0,18432): Wc staging [64][136] (17408 B) during proj;
//      after proj (barrier-protected): Q [64][72] @0, A2 [64][72] @9216.
//      RB: K [64][72] | RC: VT [64][72] | F: 448 f32
#define OFF_WC 0
#define OFF_A2 9216
#define OFF_RB 18432
#define OFF_RC 27648
#define OFF_F  36864
#define LDS_BYTES 38656
// sF: [0,192) T2h | [192,256) mask | [256,320) logits | [320,384) b1 | [384,448) w2

// ---------------- K1: xn = LN(x)*g+b, zeroed where row has no neighbors ----
__global__ __launch_bounds__(256) void k_node_ln(
    const float* __restrict__ x, const int* __restrict__ mask,
    const float* __restrict__ g, const float* __restrict__ bb,
    float* __restrict__ xn) {
  int tid = threadIdx.x;
  int row = blockIdx.x * 4 + (tid >> 6);
  int lane = tid & 63;
  float v = x[row * 64 + lane];
  float s = v;
#pragma unroll
  for (int m = 1; m < 64; m <<= 1) s += __shfl_xor(s, m, 64);
  float mean = s * (1.0f / 64.0f);
  float dv = v - mean;
  float s2 = dv * dv;
#pragma unroll
  for (int m = 1; m < 64; m <<= 1) s2 += __shfl_xor(s2, m, 64);
  float rstd = rsqrtf(s2 * (1.0f / 64.0f) + 1e-5f);
  float msum = (float)mask[row * 64 + lane];
#pragma unroll
  for (int m = 1; m < 64; m <<= 1) msum += __shfl_xor(msum, m, 64);
  float ped = (msum > 0.0f) ? 1.0f : 0.0f;
  xn[row * 64 + lane] = (dv * rstd * g[lane] + bb[lane]) * ped;
}

// ---- K2: T1s (frag-swizzled) = W[f,0:64]·xn[r]; T2[r,f] = W[f,64:128]·xn[r]+bias
// T1s layout: [((((b*3+p)*4+h)*4 + wave)*64 + lane)*16 + nt*4 + r]
__global__ __launch_bounds__(256) void k_t12(
    const float* __restrict__ xn, const float* __restrict__ W,
    const float* __restrict__ bias, float* __restrict__ T1s, float* __restrict__ T2) {
  __shared__ __align__(16) float sx[8 * 64];
  int tid = threadIdx.x;
  int r0 = blockIdx.x * 8;
#pragma unroll
  for (int u = 0; u < 2; ++u) {
    int idx = tid + 256 * u;
    sx[idx] = xn[r0 * 64 + idx];
  }
  __syncthreads();
#pragma unroll
  for (int ff = 0; ff < 3; ++ff) {
    int f = tid + 256 * ff;
    float acc1[8], acc2[8];
#pragma unroll
    for (int r = 0; r < 8; ++r) { acc1[r] = 0.f; acc2[r] = 0.f; }
    for (int e4 = 0; e4 < 64; e4 += 4) {
      float4 wa = *(const float4*)&W[f * 256 + e4];
      float4 wb = *(const float4*)&W[f * 256 + 64 + e4];
#pragma unroll
      for (int r = 0; r < 8; ++r) {
        float4 xv = *(const float4*)&sx[r * 64 + e4];
        acc1[r] += wa.x * xv.x + wa.y * xv.y + wa.z * xv.z + wa.w * xv.w;
        acc2[r] += wb.x * xv.x + wb.y * xv.y + wb.z * xv.z + wb.w * xv.w;
      }
    }
    float bv = bias[f];
    int p = f >> 8, hh = (f >> 6) & 3, nt = (f >> 4) & 3, lr = f & 15;
#pragma unroll
    for (int r = 0; r < 8; ++r) {
      int m = r0 + r;
      int bb2 = m >> 6, mm = m & 63;
      int w = mm >> 4, lh = (mm >> 2) & 3, rr = mm & 3;
      T1s[(size_t)((((bb2 * 3 + p) * 4 + hh) * 4 + w) * 64 + lh * 16 + lr) * 16 +
          nt * 4 + rr] = acc1[r];
      T2[m * 768 + f] = acc2[r] + bv;
    }
  }
}

// ---------------- K_wb: bf16 copies of W[:,128:256] and w1 ----------------
__global__ __launch_bounds__(256) void k_wb(const float* __restrict__ W,
                                            const float* __restrict__ w1,
                                            short* __restrict__ Wb,
                                            short* __restrict__ w1b) {
  int idx = blockIdx.x * 256 + threadIdx.x;
  if (idx < 12288) {  // 768 rows x 16 granules of 8
    int f = idx >> 4, gi = idx & 15;
    const float* src = &W[(size_t)f * 256 + 128 + gi * 8];
    short8 o;
#pragma unroll
    for (int i = 0; i < 8; ++i) o[i] = f2b(src[i]);
    *(short8*)&Wb[f * 128 + gi * 8] = o;
  } else if (idx < 12288 + 512) {  // 64 x 8 granules
    int g2 = idx - 12288;
    int f = g2 >> 3, gi = g2 & 7;
    const float* src = &w1[f * 64 + gi * 8];
    short8 o;
#pragma unroll
    for (int i = 0; i < 8; ++i) o[i] = f2b(src[i]);
    *(short8*)&w1b[f * 64 + gi * 8] = o;
  }
}

// ---------------- K3: fused per-(b,t,h) ----------------
__global__ __launch_bounds__(256, 4) void k_main(
    const float* __restrict__ A, const int* __restrict__ mask,
    const float* __restrict__ gu, const float* __restrict__ leg,
    const float* __restrict__ leb, const float* __restrict__ b1g,
    const float* __restrict__ w2g, const float* __restrict__ b2g,
    const float* __restrict__ T1s, const float* __restrict__ T2,
    const short* __restrict__ Wb, const short* __restrict__ w1b,
    float* __restrict__ out) {
  __shared__ __align__(16) unsigned char smem[LDS_BYTES];
  short* sWc = (short*)(smem + OFF_WC);  // Wc staging during proj
  short* sQ  = (short*)(smem + OFF_WC);  // Q after proj (barrier-protected), then w
  short* sWt = (short*)(smem + OFF_WC);
  short* sA2 = (short*)(smem + OFF_A2);
  short* sK  = (short*)(smem + OFF_RB);
  short* sVT = (short*)(smem + OFF_RC);
  float* sF  = (float*)(smem + OFF_F);

  int tid = threadIdx.x;
  int bid0 = blockIdx.x;
  int wg = (bid0 & 7) * 1024 + (bid0 >> 3);  // XCD swizzle (8192 % 8 == 0)
  int h = wg & 3, t = (wg >> 2) & 63, b = wg >> 8;
  int bt = b * 64 + t;
  int wave = tid >> 6, lane = tid & 63, lr = lane & 15, lh = lane >> 4;

  // ---- stage small constants into sF ----
  if (tid < 192) sF[tid] = T2[bt * 768 + (tid >> 6) * 256 + h * 64 + (tid & 63)];
  else sF[192 + tid - 192] = (float)mask[bt * 64 + tid - 192];
  if (tid < 64) sF[320 + tid] = b1g[tid];
  else if (tid < 128) sF[384 + tid - 64] = w2g[tid - 64];

  // ---- An LN fully in registers: wave handles its 16 M-rows ----
  short8 af[4];
  {
    int m0 = wave * 16 + lr;
    const float* Ar = A + ((size_t)((b * 64 + m0) * 64 + t)) * 128;
    float4 a4[8];
#pragma unroll
    for (int ks = 0; ks < 4; ++ks) {
      a4[2 * ks]     = *(const float4*)&Ar[ks * 32 + lh * 8];
      a4[2 * ks + 1] = *(const float4*)&Ar[ks * 32 + lh * 8 + 4];
    }
    float s = 0.f, s2 = 0.f;
#pragma unroll
    for (int q = 0; q < 8; ++q) {
      float4 u0 = a4[q];
      s += u0.x + u0.y + u0.z + u0.w;
      s2 += u0.x * u0.x + u0.y * u0.y + u0.z * u0.z + u0.w * u0.w;
    }
    s += __shfl_xor(s, 16, 64);  s += __shfl_xor(s, 32, 64);
    s2 += __shfl_xor(s2, 16, 64); s2 += __shfl_xor(s2, 32, 64);
    float mean = s * (1.0f / 128.0f);
    float var = s2 * (1.0f / 128.0f) - mean * mean;
    float rstd = rsqrtf(var + 1e-5f);
    float mv = (float)mask[bt * 64 + m0];
#pragma unroll
    for (int ks = 0; ks < 4; ++ks) {
      float4 g0 = *(const float4*)&leg[ks * 32 + lh * 8];
      float4 g1 = *(const float4*)&leg[ks * 32 + lh * 8 + 4];
      float4 c0 = *(const float4*)&leb[ks * 32 + lh * 8];
      float4 c1 = *(const float4*)&leb[ks * 32 + lh * 8 + 4];
      float gg[8] = {g0.x, g0.y, g0.z, g0.w, g1.x, g1.y, g1.z, g1.w};
      float cc[8] = {c0.x, c0.y, c0.z, c0.w, c1.x, c1.y, c1.z, c1.w};
      float4 u0 = a4[2 * ks], u1 = a4[2 * ks + 1];
      float vv[8] = {u0.x, u0.y, u0.z, u0.w, u1.x, u1.y, u1.z, u1.w};
#pragma unroll
      for (int i = 0; i < 8; ++i)
        af[ks][i] = f2b(((vv[i] - mean) * rstd * gg[i] + cc[i]) * mv);
    }
  }

  // ---- projection, part order K(p=1), V(p=2), Q(p=0 last, lands in WC) ----
#pragma unroll
  for (int pp = 0; pp < 3; ++pp) {
    const int p = (pp + 1) % 3;  // 1, 2, 0
    const int Fbase = p * 256 + h * 64;
    // stage Wc (pure bf16 copy, coalesced 16B granules)
#pragma unroll
    for (int u = 0; u < 4; ++u) {
      int idx = tid + 256 * u;
      int dR = idx >> 4, gi = idx & 15;
      *(short8*)&sWc[dR * WCS + gi * 8] =
          *(const short8*)&Wb[(size_t)(Fbase + dR) * 128 + gi * 8];
    }
    // T1 fragment preload (coalesced float4, inits the MFMA accumulator)
    float4 t1f[4];
#pragma unroll
    for (int nt = 0; nt < 4; ++nt)
      t1f[nt] = *(const float4*)&T1s[
          (size_t)((((b * 3 + p) * 4 + h) * 4 + wave) * 64 + lane) * 16 + nt * 4];
    __syncthreads();  // staging (and sF on first pass) visible
    float t2v[4];
#pragma unroll
    for (int nt = 0; nt < 4; ++nt) t2v[nt] = sF[p * 64 + nt * 16 + lr];
    f32x4 acc[4];
#pragma unroll
    for (int nt = 0; nt < 4; ++nt) {
      acc[nt][0] = t1f[nt].x; acc[nt][1] = t1f[nt].y;
      acc[nt][2] = t1f[nt].z; acc[nt][3] = t1f[nt].w;
    }
#pragma unroll
    for (int ks = 0; ks < 4; ++ks)
#pragma unroll
      for (int nt = 0; nt < 4; ++nt) {
        short8 bf = *(const short8*)&sWc[(nt * 16 + lr) * WCS + ks * 32 + lh * 8];
        acc[nt] = __builtin_amdgcn_mfma_f32_16x16x32_bf16(af[ks], bf, acc[nt], 0, 0, 0);
      }
    if (p == 0) __syncthreads();  // Q: all Wc reads drained before WC overwrite
#pragma unroll
    for (int nt = 0; nt < 4; ++nt)
#pragma unroll
      for (int r = 0; r < 4; ++r) {
        int m = wave * 16 + lh * 4 + r;
        int dcol = nt * 16 + lr;
        float val = acc[nt][r] + t2v[nt];
        if (p == 0)      sQ[m * TS + dcol] = f2b(val * 0.125f);  // * hd^-0.5
        else if (p == 1) sK[m * TS + dcol] = f2b(val);
        else             sVT[dcol * TS + m] = f2b(val);
      }
    if (p != 0) __syncthreads();  // K/V visible; Wc reads done before next stage
  }
  // NOTE: from here to logits there are NO barriers — Q/w/A2 are same-wave rows.

  // ---- scores + masked softmax (exact ref algebra) ----
  float wv[4][4];
  {
    f32x4 sc[4] = {};
#pragma unroll
    for (int ks = 0; ks < 2; ++ks) {
      short8 qf = *(const short8*)&sQ[(wave * 16 + lr) * TS + ks * 32 + lh * 8];
#pragma unroll
      for (int nt = 0; nt < 4; ++nt) {
        short8 kf = *(const short8*)&sK[(nt * 16 + lr) * TS + ks * 32 + lh * 8];
        sc[nt] = __builtin_amdgcn_mfma_f32_16x16x32_bf16(qf, kf, sc[nt], 0, 0, 0);
      }
    }
    float mk[4];
#pragma unroll
    for (int nt = 0; nt < 4; ++nt) mk[nt] = sF[192 + nt * 16 + lr];
#pragma unroll
    for (int r = 0; r < 4; ++r) {
      int j = wave * 16 + lh * 4 + r;
      float mj = sF[192 + j];
      float mx = fmaxf(fmaxf(sc[0][r], sc[1][r]), fmaxf(sc[2][r], sc[3][r]));
#pragma unroll
      for (int mm = 1; mm < 16; mm <<= 1) mx = fmaxf(mx, __shfl_xor(mx, mm, 64));
      float pv[4], Zf = 0.f, S = 0.f;
#pragma unroll
      for (int nt = 0; nt < 4; ++nt) {
        pv[nt] = expf(sc[nt][r] - mx);
        Zf += pv[nt];
        S += pv[nt] * mk[nt];
      }
#pragma unroll
      for (int mm = 1; mm < 16; mm <<= 1) {
        Zf += __shfl_xor(Zf, mm, 64);
        S += __shfl_xor(S, mm, 64);
      }
      // w = softmax*m3 renormed == p*mk*mj / (mj*S + 1e-10*Z)
      float inv = mj / (S + 1e-10f * Zf);
#pragma unroll
      for (int nt = 0; nt < 4; ++nt) wv[r][nt] = pv[nt] * mk[nt] * inv;
    }
  }
  // ---- transpose w into Q region (same-wave rows, Q already consumed) ----
#pragma unroll
  for (int r = 0; r < 4; ++r)
#pragma unroll
    for (int nt = 0; nt < 4; ++nt)
      sWt[(wave * 16 + lh * 4 + r) * TS + nt * 16 + lr] = f2b(wv[r][nt]);

  // ---- A2[j,d] = sum_k w[j,k]*v[k,d]; write @OFF_A2 (same-wave rows) ----
  {
    f32x4 a2[4] = {};
#pragma unroll
    for (int ks = 0; ks < 2; ++ks) {
      short8 wf = *(const short8*)&sWt[(wave * 16 + lr) * TS + ks * 32 + lh * 8];
#pragma unroll
      for (int nt = 0; nt < 4; ++nt) {
        short8 vf = *(const short8*)&sVT[(nt * 16 + lr) * TS + ks * 32 + lh * 8];
        a2[nt] = __builtin_amdgcn_mfma_f32_16x16x32_bf16(wf, vf, a2[nt], 0, 0, 0);
      }
    }
#pragma unroll
    for (int nt = 0; nt < 4; ++nt)
#pragma unroll
      for (int r = 0; r < 4; ++r)
        sA2[(wave * 16 + lh * 4 + r) * TS + nt * 16 + lr] = f2b(a2[nt][r]);
  }

  // ---- hmid = relu(A2·w1^T + b1); logits[j] = hmid·w2 (w1 frags from global) ----
  {
    f32x4 hm[4] = {};
#pragma unroll
    for (int ks = 0; ks < 2; ++ks) {
      short8 a2f = *(const short8*)&sA2[(wave * 16 + lr) * TS + ks * 32 + lh * 8];
#pragma unroll
      for (int nt = 0; nt < 4; ++nt) {
        short8 wf = *(const short8*)&w1b[(nt * 16 + lr) * 64 + ks * 32 + lh * 8];
        hm[nt] = __builtin_amdgcn_mfma_f32_16x16x32_bf16(a2f, wf, hm[nt], 0, 0, 0);
      }
    }
    float b1v[4], w2v[4];
#pragma unroll
    for (int nt = 0; nt < 4; ++nt) {
      b1v[nt] = sF[320 + nt * 16 + lr];
      w2v[nt] = sF[384 + nt * 16 + lr];
    }
#pragma unroll
    for (int r = 0; r < 4; ++r) {
      float pp = 0.f;
#pragma unroll
      for (int nt = 0; nt < 4; ++nt)
        pp += fmaxf(hm[nt][r] + b1v[nt], 0.f) * w2v[nt];
#pragma unroll
      for (int mm = 1; mm < 16; mm <<= 1) pp += __shfl_xor(pp, mm, 64);
      if (lr == 0) sF[256 + wave * 16 + lh * 4 + r] = pp;
    }
  }
  __syncthreads();  // logits ready

  // ---- em + gumbel + sampled (wave 0, lane j) ----
  if (tid < 64) {
    int j = tid;
    float l = sF[256 + j] + b2g[0];
    float mjv = sF[192 + j];
    float mx = l;
#pragma unroll
    for (int mm = 1; mm < 64; mm <<= 1) mx = fmaxf(mx, __shfl_xor(mx, mm, 64));
    float pv = expf(l - mx);
    float Z = pv;
#pragma unroll
    for (int mm = 1; mm < 64; mm <<= 1) Z += __shfl_xor(Z, mm, 64);
    float ep = (pv / Z) * mjv;
    float S = ep;
#pragma unroll
    for (int mm = 1; mm < 64; mm <<= 1) S += __shfl_xor(S, mm, 64);
    float em = ep / (S + 1e-10f);
    float u = gu[((size_t)bt * 4 + h) * 64 + j];
    float gg = -logf(-logf(u + 1e-10f) + 1e-10f);
    float l2 = logf(em + 1e-10f) + gg;  // TAU = 1
    float mx2 = l2;
#pragma unroll
    for (int mm = 1; mm < 64; mm <<= 1) mx2 = fmaxf(mx2, __shfl_xor(mx2, mm, 64));
    float p2 = expf(l2 - mx2);
    float Z2 = p2;
#pragma unroll
    for (int mm = 1; mm < 64; mm <<= 1) Z2 += __shfl_xor(Z2, mm, 64);
    float smp = p2 / Z2;
    size_t o = ((size_t)bt * 4 + h) * 64 + j;
    out[o] = em;
    out[524288 + o] = smp;
  }
}

extern "C" void kernel_launch(void* const* d_in, const int* in_sizes, int n_in,
                              void* d_out, int out_size, void* d_ws, size_t ws_size,
                              hipStream_t stream) {
  const float* x    = (const float*)d_in[0];
  const float* A    = (const float*)d_in[1];
  const int*   mask = (const int*)d_in[2];
  const float* gu   = (const float*)d_in[3];
  const float* lng  = (const float*)d_in[4];
  const float* lnb  = (const float*)d_in[5];
  const float* leg  = (const float*)d_in[6];
  const float* leb  = (const float*)d_in[7];
  const float* W    = (const float*)d_in[8];
  const float* bias = (const float*)d_in[9];
  const float* w1   = (const float*)d_in[10];
  const float* b1   = (const float*)d_in[11];
  const float* w2   = (const float*)d_in[12];
  const float* b2   = (const float*)d_in[13];
  float* out = (float*)d_out;
  float* ws  = (float*)d_ws;

  float* xn  = ws;                       // 131072 floats
  float* T1s = xn + 131072;              // 1572864 floats (frag-swizzled)
  float* T2  = T1s + 1572864;            // 1572864 floats
  short* Wb  = (short*)(T2 + 1572864);   // 98304 shorts
  short* w1b = Wb + 98304;               // 4096 shorts

  k_wb<<<50, 256, 0, stream>>>(W, w1, Wb, w1b);
  k_node_ln<<<512, 256, 0, stream>>>(x, mask, lng, lnb, xn);
  k_t12<<<256, 256, 0, stream>>>(xn, W, bias, T1s, T2);
  k_main<<<8192, 256, 0, stream>>>(A, mask, gu, leg, leb, b1, w2, b2,
                                   T1s, T2, Wb, w1b, out);
}

// Round 7
// 160.346 us; speedup vs baseline: 1.2586x; 1.0358x over previous
//
#include <hip/hip_runtime.h>
#include <math.h>

// EdgeSelector: B=32, N=64, D=64, H=4, E=256, HD=64
// out = [em (32,64,4,64) | sampled (32,64,4,64)] f32
// ws (floats): xn[131072] | T1s[1572864] (frag-swizzled) | T2[1572864] |
//              bf16: Wb[768*128] w1b[64*64]

typedef __attribute__((ext_vector_type(8))) short short8;   // 8 bf16 = 4 VGPR
typedef __attribute__((ext_vector_type(4))) short short4v;  // 4 bf16 = 8 B
typedef __attribute__((ext_vector_type(4))) float f32x4;

__device__ __forceinline__ short f2b(float f) {  // RNE f32->bf16
  unsigned u = __builtin_bit_cast(unsigned, f);
  unsigned r = (u + 0x7FFFu + ((u >> 16) & 1u)) >> 16;
  return (short)r;
}

#define WCS 136  // Wc row stride in shorts (272 B)
#define TS  72   // q/k/vT/A2/w row stride in shorts (144 B, 16B-aligned)

// LDS: WC region [0,18432): Wc staging [64][136] during proj;
//      after proj (barrier-protected): Q [64][72] @0 (then w), A2 [64][72] @9216.
//      RB: K [64][72] | RC: VT [64][72] | F: 448 f32
#define OFF_WC 0
#define OFF_A2 9216
#define OFF_RB 18432
#define OFF_RC 27648
#define OFF_F  36864
#define LDS_BYTES 38656
// sF: [0,192) T2h | [192,256) mask | [256,320) logits | [320,384) b1 | [384,448) w2

// ---------------- K1: xn = LN(x)*g+b, zeroed where row has no neighbors ----
__global__ __launch_bounds__(256) void k_node_ln(
    const float* __restrict__ x, const int* __restrict__ mask,
    const float* __restrict__ g, const float* __restrict__ bb,
    float* __restrict__ xn) {
  int tid = threadIdx.x;
  int row = blockIdx.x * 4 + (tid >> 6);
  int lane = tid & 63;
  float v = x[row * 64 + lane];
  float s = v;
#pragma unroll
  for (int m = 1; m < 64; m <<= 1) s += __shfl_xor(s, m, 64);
  float mean = s * (1.0f / 64.0f);
  float dv = v - mean;
  float s2 = dv * dv;
#pragma unroll
  for (int m = 1; m < 64; m <<= 1) s2 += __shfl_xor(s2, m, 64);
  float rstd = rsqrtf(s2 * (1.0f / 64.0f) + 1e-5f);
  float msum = (float)mask[row * 64 + lane];
#pragma unroll
  for (int m = 1; m < 64; m <<= 1) msum += __shfl_xor(msum, m, 64);
  float ped = (msum > 0.0f) ? 1.0f : 0.0f;
  xn[row * 64 + lane] = (dv * rstd * g[lane] + bb[lane]) * ped;
}

// ---- K2: T1s (frag-swizzled per part) ; T2[r,f] = W[f,64:128]·xn[r]+bias
// p<2 (swapped proj):  acc[nt][r] <-> (m = wave*16+lr,      d = nt*16+lh*4+r)
// p==2 (orig proj):    acc[nt][r] <-> (m = wave*16+lh*4+r,  d = nt*16+lr)
// T1s index: [((((b*3+p)*4+h)*4 + wave)*64 + lane)*16 + nt*4 + r]
__global__ __launch_bounds__(256) void k_t12(
    const float* __restrict__ xn, const float* __restrict__ W,
    const float* __restrict__ bias, float* __restrict__ T1s, float* __restrict__ T2) {
  __shared__ __align__(16) float sx[8 * 64];
  int tid = threadIdx.x;
  int r0 = blockIdx.x * 8;
#pragma unroll
  for (int u = 0; u < 2; ++u) {
    int idx = tid + 256 * u;
    sx[idx] = xn[r0 * 64 + idx];
  }
  __syncthreads();
#pragma unroll
  for (int ff = 0; ff < 3; ++ff) {
    int f = tid + 256 * ff;
    float acc1[8], acc2[8];
#pragma unroll
    for (int r = 0; r < 8; ++r) { acc1[r] = 0.f; acc2[r] = 0.f; }
    for (int e4 = 0; e4 < 64; e4 += 4) {
      float4 wa = *(const float4*)&W[f * 256 + e4];
      float4 wb = *(const float4*)&W[f * 256 + 64 + e4];
#pragma unroll
      for (int r = 0; r < 8; ++r) {
        float4 xv = *(const float4*)&sx[r * 64 + e4];
        acc1[r] += wa.x * xv.x + wa.y * xv.y + wa.z * xv.z + wa.w * xv.w;
        acc2[r] += wb.x * xv.x + wb.y * xv.y + wb.z * xv.z + wb.w * xv.w;
      }
    }
    float bv = bias[f];
    int p = f >> 8, hh = (f >> 6) & 3, dcol = f & 63;
#pragma unroll
    for (int r = 0; r < 8; ++r) {
      int m = r0 + r;
      int bb2 = m >> 6, mm = m & 63;
      int wv_ = mm >> 4;
      int lane, reg;
      if (p < 2) {
        lane = ((dcol >> 2) & 3) * 16 + (mm & 15);
        reg = (dcol >> 4) * 4 + (dcol & 3);
      } else {
        lane = ((mm >> 2) & 3) * 16 + (dcol & 15);
        reg = (dcol >> 4) * 4 + (mm & 3);
      }
      T1s[(size_t)((((bb2 * 3 + p) * 4 + hh) * 4 + wv_) * 64 + lane) * 16 + reg] =
          acc1[r];
      T2[m * 768 + f] = acc2[r] + bv;
    }
  }
}

// ---------------- K_wb: bf16 copies of W[:,128:256] and w1 ----------------
__global__ __launch_bounds__(256) void k_wb(const float* __restrict__ W,
                                            const float* __restrict__ w1,
                                            short* __restrict__ Wb,
                                            short* __restrict__ w1b) {
  int idx = blockIdx.x * 256 + threadIdx.x;
  if (idx < 12288) {  // 768 rows x 16 granules of 8
    int f = idx >> 4, gi = idx & 15;
    const float* src = &W[(size_t)f * 256 + 128 + gi * 8];
    short8 o;
#pragma unroll
    for (int i = 0; i < 8; ++i) o[i] = f2b(src[i]);
    *(short8*)&Wb[f * 128 + gi * 8] = o;
  } else if (idx < 12288 + 512) {  // 64 x 8 granules
    int g2 = idx - 12288;
    int f = g2 >> 3, gi = g2 & 7;
    const float* src = &w1[f * 64 + gi * 8];
    short8 o;
#pragma unroll
    for (int i = 0; i < 8; ++i) o[i] = f2b(src[i]);
    *(short8*)&w1b[f * 64 + gi * 8] = o;
  }
}

// ---------------- K3: fused per-(b,t,h) ----------------
__global__ __launch_bounds__(256, 4) void k_main(
    const float* __restrict__ A, const int* __restrict__ mask,
    const float* __restrict__ gu, const float* __restrict__ leg,
    const float* __restrict__ leb, const float* __restrict__ b1g,
    const float* __restrict__ w2g, const float* __restrict__ b2g,
    const float* __restrict__ T1s, const float* __restrict__ T2,
    const short* __restrict__ Wb, const short* __restrict__ w1b,
    float* __restrict__ out) {
  __shared__ __align__(16) unsigned char smem[LDS_BYTES];
  short* sWc = (short*)(smem + OFF_WC);  // Wc staging during proj
  short* sQ  = (short*)(smem + OFF_WC);  // Q after proj, then w (row-major [j][k])
  short* sWt = (short*)(smem + OFF_WC);
  short* sA2 = (short*)(smem + OFF_A2);  // A2 row-major [j][d]
  short* sK  = (short*)(smem + OFF_RB);
  short* sVT = (short*)(smem + OFF_RC);
  float* sF  = (float*)(smem + OFF_F);

  int tid = threadIdx.x;
  int bid0 = blockIdx.x;
  int wg = (bid0 & 7) * 1024 + (bid0 >> 3);  // XCD swizzle (8192 % 8 == 0)
  int h = wg & 3, t = (wg >> 2) & 63, b = wg >> 8;
  int bt = b * 64 + t;
  int wave = tid >> 6, lane = tid & 63, lr = lane & 15, lh = lane >> 4;

  // ---- stage small constants into sF ----
  if (tid < 192) sF[tid] = T2[bt * 768 + (tid >> 6) * 256 + h * 64 + (tid & 63)];
  else sF[192 + tid - 192] = (float)mask[bt * 64 + tid - 192];
  if (tid < 64) sF[320 + tid] = b1g[tid];
  else if (tid < 128) sF[384 + tid - 64] = w2g[tid - 64];

  // ---- An LN fully in registers: wave handles its 16 M-rows ----
  short8 af[4];
  {
    int m0 = wave * 16 + lr;
    const float* Ar = A + ((size_t)((b * 64 + m0) * 64 + t)) * 128;
    float4 a4[8];
#pragma unroll
    for (int ks = 0; ks < 4; ++ks) {
      a4[2 * ks]     = *(const float4*)&Ar[ks * 32 + lh * 8];
      a4[2 * ks + 1] = *(const float4*)&Ar[ks * 32 + lh * 8 + 4];
    }
    float s = 0.f, s2 = 0.f;
#pragma unroll
    for (int q = 0; q < 8; ++q) {
      float4 u0 = a4[q];
      s += u0.x + u0.y + u0.z + u0.w;
      s2 += u0.x * u0.x + u0.y * u0.y + u0.z * u0.z + u0.w * u0.w;
    }
    s += __shfl_xor(s, 16, 64);  s += __shfl_xor(s, 32, 64);
    s2 += __shfl_xor(s2, 16, 64); s2 += __shfl_xor(s2, 32, 64);
    float mean = s * (1.0f / 128.0f);
    float var = s2 * (1.0f / 128.0f) - mean * mean;
    float rstd = rsqrtf(var + 1e-5f);
    float mv = (float)mask[bt * 64 + m0];
#pragma unroll
    for (int ks = 0; ks < 4; ++ks) {
      float4 g0 = *(const float4*)&leg[ks * 32 + lh * 8];
      float4 g1 = *(const float4*)&leg[ks * 32 + lh * 8 + 4];
      float4 c0 = *(const float4*)&leb[ks * 32 + lh * 8];
      float4 c1 = *(const float4*)&leb[ks * 32 + lh * 8 + 4];
      float gg[8] = {g0.x, g0.y, g0.z, g0.w, g1.x, g1.y, g1.z, g1.w};
      float cc[8] = {c0.x, c0.y, c0.z, c0.w, c1.x, c1.y, c1.z, c1.w};
      float4 u0 = a4[2 * ks], u1 = a4[2 * ks + 1];
      float vv[8] = {u0.x, u0.y, u0.z, u0.w, u1.x, u1.y, u1.z, u1.w};
#pragma unroll
      for (int i = 0; i < 8; ++i)
        af[ks][i] = f2b(((vv[i] - mean) * rstd * gg[i] + cc[i]) * mv);
    }
  }

  // ---- projection, part order K(p=1), V(p=2), Q(p=0 last, lands in WC) ----
#pragma unroll
  for (int pp = 0; pp < 3; ++pp) {
    const int p = (pp + 1) % 3;  // 1, 2, 0
    const int Fbase = p * 256 + h * 64;
    // stage Wc (pure bf16 copy, coalesced 16B granules)
#pragma unroll
    for (int u = 0; u < 4; ++u) {
      int idx = tid + 256 * u;
      int dR = idx >> 4, gi = idx & 15;
      *(short8*)&sWc[dR * WCS + gi * 8] =
          *(const short8*)&Wb[(size_t)(Fbase + dR) * 128 + gi * 8];
    }
    // T1 fragment preload (coalesced float4, inits the MFMA accumulator)
    float4 t1f[4];
#pragma unroll
    for (int nt = 0; nt < 4; ++nt)
      t1f[nt] = *(const float4*)&T1s[
          (size_t)((((b * 3 + p) * 4 + h) * 4 + wave) * 64 + lane) * 16 + nt * 4];
    __syncthreads();  // staging (and sF on first pass) visible
    f32x4 acc[4];
#pragma unroll
    for (int nt = 0; nt < 4; ++nt) {
      acc[nt][0] = t1f[nt].x; acc[nt][1] = t1f[nt].y;
      acc[nt][2] = t1f[nt].z; acc[nt][3] = t1f[nt].w;
    }
    if (p == 2) {
      // original orientation: acc[nt][r] = qkv[m=wave*16+lh*4+r][d=nt*16+lr]
#pragma unroll
      for (int ks = 0; ks < 4; ++ks)
#pragma unroll
        for (int nt = 0; nt < 4; ++nt) {
          short8 bf = *(const short8*)&sWc[(nt * 16 + lr) * WCS + ks * 32 + lh * 8];
          acc[nt] = __builtin_amdgcn_mfma_f32_16x16x32_bf16(af[ks], bf, acc[nt], 0, 0, 0);
        }
    } else {
      // swapped: acc[nt][r] = qkv[m=wave*16+lr][d=nt*16+lh*4+r]
#pragma unroll
      for (int ks = 0; ks < 4; ++ks)
#pragma unroll
        for (int nt = 0; nt < 4; ++nt) {
          short8 bf = *(const short8*)&sWc[(nt * 16 + lr) * WCS + ks * 32 + lh * 8];
          acc[nt] = __builtin_amdgcn_mfma_f32_16x16x32_bf16(bf, af[ks], acc[nt], 0, 0, 0);
        }
    }
    if (p == 0) __syncthreads();  // Q: all Wc reads drained before WC overwrite
    if (p == 2) {
      float t2v[4];
#pragma unroll
      for (int nt = 0; nt < 4; ++nt) t2v[nt] = sF[128 + nt * 16 + lr];
#pragma unroll
      for (int nt = 0; nt < 4; ++nt) {
        short4v vp;
#pragma unroll
        for (int r = 0; r < 4; ++r) vp[r] = f2b(acc[nt][r] + t2v[nt]);
        *(short4v*)&sVT[(nt * 16 + lr) * TS + wave * 16 + lh * 4] = vp;
      }
    } else {
      float scale = (p == 0) ? 0.125f : 1.0f;  // hd^-0.5 on q
      short* dst = (p == 0) ? sQ : sK;
#pragma unroll
      for (int nt = 0; nt < 4; ++nt) {
        float4 t24 = *(const float4*)&sF[p * 64 + nt * 16 + lh * 4];
        float tv[4] = {t24.x, t24.y, t24.z, t24.w};
        short4v qp;
#pragma unroll
        for (int r = 0; r < 4; ++r) qp[r] = f2b((acc[nt][r] + tv[r]) * scale);
        *(short4v*)&dst[(wave * 16 + lr) * TS + nt * 16 + lh * 4] = qp;
      }
    }
    if (p != 0) __syncthreads();  // K/V visible; Wc reads done before next stage
  }
  // From here to logits: NO barriers — all LDS round-trips are same-wave rows.

  // ---- scores (transposed): sc[nt][r] = scores[j=wave*16+lr][k=nt*16+lh*4+r]
  {
    f32x4 sc[4] = {};
#pragma unroll
    for (int ks = 0; ks < 2; ++ks) {
      short8 qf = *(const short8*)&sQ[(wave * 16 + lr) * TS + ks * 32 + lh * 8];
#pragma unroll
      for (int nt = 0; nt < 4; ++nt) {
        short8 kf = *(const short8*)&sK[(nt * 16 + lr) * TS + ks * 32 + lh * 8];
        sc[nt] = __builtin_amdgcn_mfma_f32_16x16x32_bf16(kf, qf, sc[nt], 0, 0, 0);
      }
    }
    // softmax over k (per-lane 16 values + 2 shuffles across lh groups)
    float mj = sF[192 + wave * 16 + lr];
    float mx = sc[0][0];
#pragma unroll
    for (int nt = 0; nt < 4; ++nt)
#pragma unroll
      for (int r = 0; r < 4; ++r) mx = fmaxf(mx, sc[nt][r]);
    mx = fmaxf(mx, __shfl_xor(mx, 16, 64));
    mx = fmaxf(mx, __shfl_xor(mx, 32, 64));
    float pv[4][4], mkv[4][4], Zf = 0.f, S = 0.f;
#pragma unroll
    for (int nt = 0; nt < 4; ++nt) {
      float4 mk4 = *(const float4*)&sF[192 + nt * 16 + lh * 4];
      float mk[4] = {mk4.x, mk4.y, mk4.z, mk4.w};
#pragma unroll
      for (int r = 0; r < 4; ++r) {
        float e = expf(sc[nt][r] - mx);
        pv[nt][r] = e;
        mkv[nt][r] = mk[r];
        Zf += e;
        S += e * mk[r];
      }
    }
    Zf += __shfl_xor(Zf, 16, 64); Zf += __shfl_xor(Zf, 32, 64);
    S  += __shfl_xor(S, 16, 64);  S  += __shfl_xor(S, 32, 64);
    // w = softmax*m3 renormed == p*mk*mj / (mj*S + 1e-10*Z)
    float inv = mj / (S + 1e-10f * Zf);
    // write w row-major [j][k], packed b64 (overwrites Q region, same-wave row)
#pragma unroll
    for (int nt = 0; nt < 4; ++nt) {
      short4v wp;
#pragma unroll
      for (int r = 0; r < 4; ++r) wp[r] = f2b(pv[nt][r] * mkv[nt][r] * inv);
      *(short4v*)&sWt[(wave * 16 + lr) * TS + nt * 16 + lh * 4] = wp;
    }
  }

  // ---- A2 (transposed): a2[nt][r] = A2[j=wave*16+lr][d=nt*16+lh*4+r] ----
  {
    f32x4 a2[4] = {};
#pragma unroll
    for (int ks = 0; ks < 2; ++ks) {
      short8 wf = *(const short8*)&sWt[(wave * 16 + lr) * TS + ks * 32 + lh * 8];
#pragma unroll
      for (int nt = 0; nt < 4; ++nt) {
        short8 vf = *(const short8*)&sVT[(nt * 16 + lr) * TS + ks * 32 + lh * 8];
        a2[nt] = __builtin_amdgcn_mfma_f32_16x16x32_bf16(vf, wf, a2[nt], 0, 0, 0);
      }
    }
    // A2 row-major [j][d], packed b64 (same-wave row)
#pragma unroll
    for (int nt = 0; nt < 4; ++nt) {
      short4v ap;
#pragma unroll
      for (int r = 0; r < 4; ++r) ap[r] = f2b(a2[nt][r]);
      *(short4v*)&sA2[(wave * 16 + lr) * TS + nt * 16 + lh * 4] = ap;
    }
  }

  // ---- hmid (transposed): hm[nt][r] = hmid[o=nt*16+lh*4+r][j=wave*16+lr] ----
  {
    f32x4 hm[4] = {};
#pragma unroll
    for (int ks = 0; ks < 2; ++ks) {
      short8 a2f = *(const short8*)&sA2[(wave * 16 + lr) * TS + ks * 32 + lh * 8];
#pragma unroll
      for (int nt = 0; nt < 4; ++nt) {
        short8 wf = *(const short8*)&w1b[(nt * 16 + lr) * 64 + ks * 32 + lh * 8];
        hm[nt] = __builtin_amdgcn_mfma_f32_16x16x32_bf16(wf, a2f, hm[nt], 0, 0, 0);
      }
    }
    float pp = 0.f;
#pragma unroll
    for (int nt = 0; nt < 4; ++nt) {
      float4 b14 = *(const float4*)&sF[320 + nt * 16 + lh * 4];
      float4 w24 = *(const float4*)&sF[384 + nt * 16 + lh * 4];
      float bb4[4] = {b14.x, b14.y, b14.z, b14.w};
      float ww4[4] = {w24.x, w24.y, w24.z, w24.w};
#pragma unroll
      for (int r = 0; r < 4; ++r)
        pp += fmaxf(hm[nt][r] + bb4[r], 0.f) * ww4[r];
    }
    pp += __shfl_xor(pp, 16, 64);
    pp += __shfl_xor(pp, 32, 64);
    if (lh == 0) sF[256 + wave * 16 + lr] = pp;
  }
  __syncthreads();  // logits ready

  // ---- em + gumbel + sampled (wave 0, lane j) ----
  if (tid < 64) {
    int j = tid;
    float l = sF[256 + j] + b2g[0];
    float mjv = sF[192 + j];
    float mx = l;
#pragma unroll
    for (int mm = 1; mm < 64; mm <<= 1) mx = fmaxf(mx, __shfl_xor(mx, mm, 64));
    float pv = expf(l - mx);
    float Z = pv;
#pragma unroll
    for (int mm = 1; mm < 64; mm <<= 1) Z += __shfl_xor(Z, mm, 64);
    float ep = (pv / Z) * mjv;
    float S = ep;
#pragma unroll
    for (int mm = 1; mm < 64; mm <<= 1) S += __shfl_xor(S, mm, 64);
    float em = ep / (S + 1e-10f);
    float u = gu[((size_t)bt * 4 + h) * 64 + j];
    float gg = -logf(-logf(u + 1e-10f) + 1e-10f);
    float l2 = logf(em + 1e-10f) + gg;  // TAU = 1
    float mx2 = l2;
#pragma unroll
    for (int mm = 1; mm < 64; mm <<= 1) mx2 = fmaxf(mx2, __shfl_xor(mx2, mm, 64));
    float p2 = expf(l2 - mx2);
    float Z2 = p2;
#pragma unroll
    for (int mm = 1; mm < 64; mm <<= 1) Z2 += __shfl_xor(Z2, mm, 64);
    float smp = p2 / Z2;
    size_t o = ((size_t)bt * 4 + h) * 64 + j;
    out[o] = em;
    out[524288 + o] = smp;
  }
}

extern "C" void kernel_launch(void* const* d_in, const int* in_sizes, int n_in,
                              void* d_out, int out_size, void* d_ws, size_t ws_size,
                              hipStream_t stream) {
  const float* x    = (const float*)d_in[0];
  const float* A    = (const float*)d_in[1];
  const int*   mask = (const int*)d_in[2];
  const float* gu   = (const float*)d_in[3];
  const float* lng  = (const float*)d_in[4];
  const float* lnb  = (const float*)d_in[5];
  const float* leg  = (const float*)d_in[6];
  const float* leb  = (const float*)d_in[7];
  const float* W    = (const float*)d_in[8];
  const float* bias = (const float*)d_in[9];
  const float* w1   = (const float*)d_in[10];
  const float* b1   = (const float*)d_in[11];
  const float* w2   = (const float*)d_in[12];
  const float* b2   = (const float*)d_in[13];
  float* out = (float*)d_out;
  float* ws  = (float*)d_ws;

  float* xn  = ws;                       // 131072 floats
  float* T1s = xn + 131072;              // 1572864 floats (frag-swizzled)
  float* T2  = T1s + 1572864;            // 1572864 floats
  short* Wb  = (short*)(T2 + 1572864);   // 98304 shorts
  short* w1b = Wb + 98304;               // 4096 shorts

  k_wb<<<50, 256, 0, stream>>>(W, w1, Wb, w1b);
  k_node_ln<<<512, 256, 0, stream>>>(x, mask, lng, lnb, xn);
  k_t12<<<256, 256, 0, stream>>>(xn, W, bias, T1s, T2);
  k_main<<<8192, 256, 0, stream>>>(A, mask, gu, leg, leb, b1, w2, b2,
                                   T1s, T2, Wb, w1b, out);
}

// Round 8
// 128.593 us; speedup vs baseline: 1.5694x; 1.2469x over previous
//
#include <hip/hip_runtime.h>
#include <hip/hip_bf16.h>
#include <math.h>

// EdgeSelector: B=32, N=64, D=64, H=4, E=256, HD=64
// out = [em (32,64,4,64) | sampled (32,64,4,64)] f32
// ws (floats): xn[131072] | T1s[1572864] (frag-swizzled) | T2[1572864] |
//              bf16: Wb[768*128] w1b[64*64]

typedef __attribute__((ext_vector_type(8))) short short8;   // 8 bf16 = 4 VGPR
typedef __attribute__((ext_vector_type(4))) short short4v;  // 4 bf16 = 8 B
typedef __attribute__((ext_vector_type(4))) float f32x4;

__device__ __forceinline__ short f2b(float f) {  // RNE via HW cvt (packs to cvt_pk)
  return (short)__builtin_bit_cast(unsigned short, __float2bfloat16(f));
}

#define WCS 136  // Wc row stride in shorts (272 B)
#define TS  72   // q/k/vT/A2/w row stride in shorts (144 B, 16B-aligned)

// LDS: WC region [0,18432): Wc staging [64][136] during proj;
//      after proj (barrier-protected): Q [64][72] @0 (then w), A2 [64][72] @9216.
//      RB: K [64][72] | RC: VT [64][72] | F: 640 f32
#define OFF_WC 0
#define OFF_A2 9216
#define OFF_RB 18432
#define OFF_RC 27648
#define OFF_F  36864
#define LDS_BYTES 39424
// sF: [0,192) T2h(current head) | [192,256) mask | [256,320) b1 | [320,384) w2 |
//     [384,640) logits (4 heads x 64)

// ---------------- K1: xn = LN(x)*g+b, zeroed where row has no neighbors ----
__global__ __launch_bounds__(256) void k_node_ln(
    const float* __restrict__ x, const int* __restrict__ mask,
    const float* __restrict__ g, const float* __restrict__ bb,
    float* __restrict__ xn) {
  int tid = threadIdx.x;
  int row = blockIdx.x * 4 + (tid >> 6);
  int lane = tid & 63;
  float v = x[row * 64 + lane];
  float s = v;
#pragma unroll
  for (int m = 1; m < 64; m <<= 1) s += __shfl_xor(s, m, 64);
  float mean = s * (1.0f / 64.0f);
  float dv = v - mean;
  float s2 = dv * dv;
#pragma unroll
  for (int m = 1; m < 64; m <<= 1) s2 += __shfl_xor(s2, m, 64);
  float rstd = rsqrtf(s2 * (1.0f / 64.0f) + 1e-5f);
  float msum = (float)mask[row * 64 + lane];
#pragma unroll
  for (int m = 1; m < 64; m <<= 1) msum += __shfl_xor(msum, m, 64);
  float ped = (msum > 0.0f) ? 1.0f : 0.0f;
  xn[row * 64 + lane] = (dv * rstd * g[lane] + bb[lane]) * ped;
}

// ---- K2: T1s (frag-swizzled per part) ; T2[r,f] = W[f,64:128]·xn[r]+bias
// p<2 (swapped proj):  acc[nt][r] <-> (m = wave*16+lr,      d = nt*16+lh*4+r)
// p==2 (orig proj):    acc[nt][r] <-> (m = wave*16+lh*4+r,  d = nt*16+lr)
// T1s index: [((((b*3+p)*4+h)*4 + wave)*64 + lane)*16 + nt*4 + r]
__global__ __launch_bounds__(256) void k_t12(
    const float* __restrict__ xn, const float* __restrict__ W,
    const float* __restrict__ bias, float* __restrict__ T1s, float* __restrict__ T2) {
  __shared__ __align__(16) float sx[8 * 64];
  int tid = threadIdx.x;
  int r0 = blockIdx.x * 8;
#pragma unroll
  for (int u = 0; u < 2; ++u) {
    int idx = tid + 256 * u;
    sx[idx] = xn[r0 * 64 + idx];
  }
  __syncthreads();
#pragma unroll
  for (int ff = 0; ff < 3; ++ff) {
    int f = tid + 256 * ff;
    float acc1[8], acc2[8];
#pragma unroll
    for (int r = 0; r < 8; ++r) { acc1[r] = 0.f; acc2[r] = 0.f; }
    for (int e4 = 0; e4 < 64; e4 += 4) {
      float4 wa = *(const float4*)&W[f * 256 + e4];
      float4 wb = *(const float4*)&W[f * 256 + 64 + e4];
#pragma unroll
      for (int r = 0; r < 8; ++r) {
        float4 xv = *(const float4*)&sx[r * 64 + e4];
        acc1[r] += wa.x * xv.x + wa.y * xv.y + wa.z * xv.z + wa.w * xv.w;
        acc2[r] += wb.x * xv.x + wb.y * xv.y + wb.z * xv.z + wb.w * xv.w;
      }
    }
    float bv = bias[f];
    int p = f >> 8, hh = (f >> 6) & 3, dcol = f & 63;
#pragma unroll
    for (int r = 0; r < 8; ++r) {
      int m = r0 + r;
      int bb2 = m >> 6, mm = m & 63;
      int wv_ = mm >> 4;
      int lane, reg;
      if (p < 2) {
        lane = ((dcol >> 2) & 3) * 16 + (mm & 15);
        reg = (dcol >> 4) * 4 + (dcol & 3);
      } else {
        lane = ((mm >> 2) & 3) * 16 + (dcol & 15);
        reg = (dcol >> 4) * 4 + (mm & 3);
      }
      T1s[(size_t)((((bb2 * 3 + p) * 4 + hh) * 4 + wv_) * 64 + lane) * 16 + reg] =
          acc1[r];
      T2[m * 768 + f] = acc2[r] + bv;
    }
  }
}

// ---------------- K_wb: bf16 copies of W[:,128:256] and w1 ----------------
__global__ __launch_bounds__(256) void k_wb(const float* __restrict__ W,
                                            const float* __restrict__ w1,
                                            short* __restrict__ Wb,
                                            short* __restrict__ w1b) {
  int idx = blockIdx.x * 256 + threadIdx.x;
  if (idx < 12288) {  // 768 rows x 16 granules of 8
    int f = idx >> 4, gi = idx & 15;
    const float* src = &W[(size_t)f * 256 + 128 + gi * 8];
    short8 o;
#pragma unroll
    for (int i = 0; i < 8; ++i) o[i] = f2b(src[i]);
    *(short8*)&Wb[f * 128 + gi * 8] = o;
  } else if (idx < 12288 + 512) {  // 64 x 8 granules
    int g2 = idx - 12288;
    int f = g2 >> 3, gi = g2 & 7;
    const float* src = &w1[f * 64 + gi * 8];
    short8 o;
#pragma unroll
    for (int i = 0; i < 8; ++i) o[i] = f2b(src[i]);
    *(short8*)&w1b[f * 64 + gi * 8] = o;
  }
}

// ---------------- K3: fused per-(b,t), 4 heads sequential ----------------
__global__ __launch_bounds__(256, 4) void k_main(
    const float* __restrict__ A, const int* __restrict__ mask,
    const float* __restrict__ gu, const float* __restrict__ leg,
    const float* __restrict__ leb, const float* __restrict__ b1g,
    const float* __restrict__ w2g, const float* __restrict__ b2g,
    const float* __restrict__ T1s, const float* __restrict__ T2,
    const short* __restrict__ Wb, const short* __restrict__ w1b,
    float* __restrict__ out) {
  __shared__ __align__(16) unsigned char smem[LDS_BYTES];
  short* sWc = (short*)(smem + OFF_WC);  // Wc staging during proj
  short* sQ  = (short*)(smem + OFF_WC);  // Q after proj, then w (row-major [j][k])
  short* sWt = (short*)(smem + OFF_WC);
  short* sA2 = (short*)(smem + OFF_A2);  // A2 row-major [j][d]
  short* sK  = (short*)(smem + OFF_RB);
  short* sVT = (short*)(smem + OFF_RC);
  float* sF  = (float*)(smem + OFF_F);

  int tid = threadIdx.x;
  int bid0 = blockIdx.x;
  int wg = (bid0 & 7) * 256 + (bid0 >> 3);  // XCD swizzle (2048 % 8 == 0)
  int t = wg & 63, b = wg >> 6;
  int bt = b * 64 + t;
  int wave = tid >> 6, lane = tid & 63, lr = lane & 15, lh = lane >> 4;

  // ---- stage block constants: mask, b1, w2 ----
  if (tid < 64) sF[192 + tid] = (float)mask[bt * 64 + tid];
  else if (tid < 128) sF[256 + tid - 64] = b1g[tid - 64];
  else if (tid < 192) sF[320 + tid - 128] = w2g[tid - 128];

  // ---- An LN fully in registers, ONCE per (b,t): wave handles its 16 M-rows ----
  short8 af[4];
  {
    int m0 = wave * 16 + lr;
    const float* Ar = A + ((size_t)((b * 64 + m0) * 64 + t)) * 128;
    float4 a4[8];
#pragma unroll
    for (int ks = 0; ks < 4; ++ks) {
      a4[2 * ks]     = *(const float4*)&Ar[ks * 32 + lh * 8];
      a4[2 * ks + 1] = *(const float4*)&Ar[ks * 32 + lh * 8 + 4];
    }
    float s = 0.f, s2 = 0.f;
#pragma unroll
    for (int q = 0; q < 8; ++q) {
      float4 u0 = a4[q];
      s += u0.x + u0.y + u0.z + u0.w;
      s2 += u0.x * u0.x + u0.y * u0.y + u0.z * u0.z + u0.w * u0.w;
    }
    s += __shfl_xor(s, 16, 64);  s += __shfl_xor(s, 32, 64);
    s2 += __shfl_xor(s2, 16, 64); s2 += __shfl_xor(s2, 32, 64);
    float mean = s * (1.0f / 128.0f);
    float var = s2 * (1.0f / 128.0f) - mean * mean;
    float rstd = rsqrtf(var + 1e-5f);
    float mv = (float)mask[bt * 64 + m0];
#pragma unroll
    for (int ks = 0; ks < 4; ++ks) {
      float4 g0 = *(const float4*)&leg[ks * 32 + lh * 8];
      float4 g1 = *(const float4*)&leg[ks * 32 + lh * 8 + 4];
      float4 c0 = *(const float4*)&leb[ks * 32 + lh * 8];
      float4 c1 = *(const float4*)&leb[ks * 32 + lh * 8 + 4];
      float gg[8] = {g0.x, g0.y, g0.z, g0.w, g1.x, g1.y, g1.z, g1.w};
      float cc[8] = {c0.x, c0.y, c0.z, c0.w, c1.x, c1.y, c1.z, c1.w};
      float4 u0 = a4[2 * ks], u1 = a4[2 * ks + 1];
      float vv[8] = {u0.x, u0.y, u0.z, u0.w, u1.x, u1.y, u1.z, u1.w};
#pragma unroll
      for (int i = 0; i < 8; ++i)
        af[ks][i] = f2b(((vv[i] - mean) * rstd * gg[i] + cc[i]) * mv);
    }
  }

#pragma unroll 1
  for (int h = 0; h < 4; ++h) {
    __syncthreads();  // fence: previous head (or prologue) fully complete
    // stage this head's T2h (visible at next barrier)
    if (tid < 192) sF[tid] = T2[bt * 768 + (tid >> 6) * 256 + h * 64 + (tid & 63)];

    // ---- projection, part order K(p=1), V(p=2), Q(p=0 last, lands in WC) ----
#pragma unroll
    for (int pp = 0; pp < 3; ++pp) {
      const int p = (pp + 1) % 3;  // 1, 2, 0
      const int Fbase = p * 256 + h * 64;
      // stage Wc (pure bf16 copy, coalesced 16B granules)
#pragma unroll
      for (int u = 0; u < 4; ++u) {
        int idx = tid + 256 * u;
        int dR = idx >> 4, gi = idx & 15;
        *(short8*)&sWc[dR * WCS + gi * 8] =
            *(const short8*)&Wb[(size_t)(Fbase + dR) * 128 + gi * 8];
      }
      // T1 fragment preload (coalesced float4, inits the MFMA accumulator)
      float4 t1f[4];
#pragma unroll
      for (int nt = 0; nt < 4; ++nt)
        t1f[nt] = *(const float4*)&T1s[
            (size_t)((((b * 3 + p) * 4 + h) * 4 + wave) * 64 + lane) * 16 + nt * 4];
      __syncthreads();  // staging (Wc, and T2h on pp=0) visible
      f32x4 acc[4];
#pragma unroll
      for (int nt = 0; nt < 4; ++nt) {
        acc[nt][0] = t1f[nt].x; acc[nt][1] = t1f[nt].y;
        acc[nt][2] = t1f[nt].z; acc[nt][3] = t1f[nt].w;
      }
      if (p == 2) {
        // original orientation: acc[nt][r] = qkv[m=wave*16+lh*4+r][d=nt*16+lr]
#pragma unroll
        for (int ks = 0; ks < 4; ++ks)
#pragma unroll
          for (int nt = 0; nt < 4; ++nt) {
            short8 bf = *(const short8*)&sWc[(nt * 16 + lr) * WCS + ks * 32 + lh * 8];
            acc[nt] = __builtin_amdgcn_mfma_f32_16x16x32_bf16(af[ks], bf, acc[nt], 0, 0, 0);
          }
      } else {
        // swapped: acc[nt][r] = qkv[m=wave*16+lr][d=nt*16+lh*4+r]
#pragma unroll
        for (int ks = 0; ks < 4; ++ks)
#pragma unroll
          for (int nt = 0; nt < 4; ++nt) {
            short8 bf = *(const short8*)&sWc[(nt * 16 + lr) * WCS + ks * 32 + lh * 8];
            acc[nt] = __builtin_amdgcn_mfma_f32_16x16x32_bf16(bf, af[ks], acc[nt], 0, 0, 0);
          }
      }
      if (p == 0) __syncthreads();  // Q: all Wc reads drained before WC overwrite
      if (p == 2) {
        float t2v[4];
#pragma unroll
        for (int nt = 0; nt < 4; ++nt) t2v[nt] = sF[128 + nt * 16 + lr];
#pragma unroll
        for (int nt = 0; nt < 4; ++nt) {
          short4v vp;
#pragma unroll
          for (int r = 0; r < 4; ++r) vp[r] = f2b(acc[nt][r] + t2v[nt]);
          *(short4v*)&sVT[(nt * 16 + lr) * TS + wave * 16 + lh * 4] = vp;
        }
      } else {
        float scale = (p == 0) ? 0.125f : 1.0f;  // hd^-0.5 on q
        short* dst = (p == 0) ? sQ : sK;
#pragma unroll
        for (int nt = 0; nt < 4; ++nt) {
          float4 t24 = *(const float4*)&sF[p * 64 + nt * 16 + lh * 4];
          float tv[4] = {t24.x, t24.y, t24.z, t24.w};
          short4v qp;
#pragma unroll
          for (int r = 0; r < 4; ++r) qp[r] = f2b((acc[nt][r] + tv[r]) * scale);
          *(short4v*)&dst[(wave * 16 + lr) * TS + nt * 16 + lh * 4] = qp;
        }
      }
      if (p != 0) __syncthreads();  // K/V visible; Wc reads done before next stage
    }
    // From here to logits: NO barriers — all LDS round-trips are same-wave rows.

    // ---- scores (transposed): sc[nt][r] = scores[j=wave*16+lr][k=nt*16+lh*4+r]
    {
      f32x4 sc[4] = {};
#pragma unroll
      for (int ks = 0; ks < 2; ++ks) {
        short8 qf = *(const short8*)&sQ[(wave * 16 + lr) * TS + ks * 32 + lh * 8];
#pragma unroll
        for (int nt = 0; nt < 4; ++nt) {
          short8 kf = *(const short8*)&sK[(nt * 16 + lr) * TS + ks * 32 + lh * 8];
          sc[nt] = __builtin_amdgcn_mfma_f32_16x16x32_bf16(kf, qf, sc[nt], 0, 0, 0);
        }
      }
      // softmax over k (per-lane 16 values + 2 shuffles across lh groups)
      float mj = sF[192 + wave * 16 + lr];
      float mx = sc[0][0];
#pragma unroll
      for (int nt = 0; nt < 4; ++nt)
#pragma unroll
        for (int r = 0; r < 4; ++r) mx = fmaxf(mx, sc[nt][r]);
      mx = fmaxf(mx, __shfl_xor(mx, 16, 64));
      mx = fmaxf(mx, __shfl_xor(mx, 32, 64));
      float pv[4][4], mkv[4][4], Zf = 0.f, S = 0.f;
#pragma unroll
      for (int nt = 0; nt < 4; ++nt) {
        float4 mk4 = *(const float4*)&sF[192 + nt * 16 + lh * 4];
        float mk[4] = {mk4.x, mk4.y, mk4.z, mk4.w};
#pragma unroll
        for (int r = 0; r < 4; ++r) {
          float e = __expf(sc[nt][r] - mx);
          pv[nt][r] = e;
          mkv[nt][r] = mk[r];
          Zf += e;
          S += e * mk[r];
        }
      }
      Zf += __shfl_xor(Zf, 16, 64); Zf += __shfl_xor(Zf, 32, 64);
      S  += __shfl_xor(S, 16, 64);  S  += __shfl_xor(S, 32, 64);
      // w = softmax*m3 renormed == p*mk*mj / (mj*S + 1e-10*Z)
      float inv = mj / (S + 1e-10f * Zf);
      // write w row-major [j][k], packed b64 (overwrites Q region, same-wave row)
#pragma unroll
      for (int nt = 0; nt < 4; ++nt) {
        short4v wp;
#pragma unroll
        for (int r = 0; r < 4; ++r) wp[r] = f2b(pv[nt][r] * mkv[nt][r] * inv);
        *(short4v*)&sWt[(wave * 16 + lr) * TS + nt * 16 + lh * 4] = wp;
      }
    }

    // ---- A2 (transposed): a2[nt][r] = A2[j=wave*16+lr][d=nt*16+lh*4+r] ----
    {
      f32x4 a2[4] = {};
#pragma unroll
      for (int ks = 0; ks < 2; ++ks) {
        short8 wf = *(const short8*)&sWt[(wave * 16 + lr) * TS + ks * 32 + lh * 8];
#pragma unroll
        for (int nt = 0; nt < 4; ++nt) {
          short8 vf = *(const short8*)&sVT[(nt * 16 + lr) * TS + ks * 32 + lh * 8];
          a2[nt] = __builtin_amdgcn_mfma_f32_16x16x32_bf16(vf, wf, a2[nt], 0, 0, 0);
        }
      }
      // A2 row-major [j][d], packed b64 (same-wave row)
#pragma unroll
      for (int nt = 0; nt < 4; ++nt) {
        short4v ap;
#pragma unroll
        for (int r = 0; r < 4; ++r) ap[r] = f2b(a2[nt][r]);
        *(short4v*)&sA2[(wave * 16 + lr) * TS + nt * 16 + lh * 4] = ap;
      }
    }

    // ---- hmid (transposed): hm[nt][r] = hmid[o=nt*16+lh*4+r][j=wave*16+lr] ----
    {
      f32x4 hm[4] = {};
#pragma unroll
      for (int ks = 0; ks < 2; ++ks) {
        short8 a2f = *(const short8*)&sA2[(wave * 16 + lr) * TS + ks * 32 + lh * 8];
#pragma unroll
        for (int nt = 0; nt < 4; ++nt) {
          short8 wf = *(const short8*)&w1b[(nt * 16 + lr) * 64 + ks * 32 + lh * 8];
          hm[nt] = __builtin_amdgcn_mfma_f32_16x16x32_bf16(wf, a2f, hm[nt], 0, 0, 0);
        }
      }
      float pp_ = 0.f;
#pragma unroll
      for (int nt = 0; nt < 4; ++nt) {
        float4 b14 = *(const float4*)&sF[256 + nt * 16 + lh * 4];
        float4 w24 = *(const float4*)&sF[320 + nt * 16 + lh * 4];
        float bb4[4] = {b14.x, b14.y, b14.z, b14.w};
        float ww4[4] = {w24.x, w24.y, w24.z, w24.w};
#pragma unroll
        for (int r = 0; r < 4; ++r)
          pp_ += fmaxf(hm[nt][r] + bb4[r], 0.f) * ww4[r];
      }
      pp_ += __shfl_xor(pp_, 16, 64);
      pp_ += __shfl_xor(pp_, 32, 64);
      if (lh == 0) sF[384 + h * 64 + wave * 16 + lr] = pp_;
    }
  }
  __syncthreads();  // all 4 heads' logits visible

  // ---- parallel tails: wave handles head h = wave ----
  {
    int hh = wave, j = lane;
    float l = sF[384 + hh * 64 + j] + b2g[0];
    float mjv = sF[192 + j];
    float mx = l;
#pragma unroll
    for (int mm = 1; mm < 64; mm <<= 1) mx = fmaxf(mx, __shfl_xor(mx, mm, 64));
    float pv = __expf(l - mx);
    float Z = pv;
#pragma unroll
    for (int mm = 1; mm < 64; mm <<= 1) Z += __shfl_xor(Z, mm, 64);
    float ep = (pv / Z) * mjv;
    float S = ep;
#pragma unroll
    for (int mm = 1; mm < 64; mm <<= 1) S += __shfl_xor(S, mm, 64);
    float em = ep / (S + 1e-10f);
    float u = gu[((size_t)bt * 4 + hh) * 64 + j];
    float gg = -__logf(-__logf(u + 1e-10f) + 1e-10f);
    float l2 = __logf(em + 1e-10f) + gg;  // TAU = 1
    float mx2 = l2;
#pragma unroll
    for (int mm = 1; mm < 64; mm <<= 1) mx2 = fmaxf(mx2, __shfl_xor(mx2, mm, 64));
    float p2 = __expf(l2 - mx2);
    float Z2 = p2;
#pragma unroll
    for (int mm = 1; mm < 64; mm <<= 1) Z2 += __shfl_xor(Z2, mm, 64);
    float smp = p2 / Z2;
    size_t o = ((size_t)bt * 4 + hh) * 64 + j;
    out[o] = em;
    out[524288 + o] = smp;
  }
}

extern "C" void kernel_launch(void* const* d_in, const int* in_sizes, int n_in,
                              void* d_out, int out_size, void* d_ws, size_t ws_size,
                              hipStream_t stream) {
  const float* x    = (const float*)d_in[0];
  const float* A    = (const float*)d_in[1];
  const int*   mask = (const int*)d_in[2];
  const float* gu   = (const float*)d_in[3];
  const float* lng  = (const float*)d_in[4];
  const float* lnb  = (const float*)d_in[5];
  const float* leg  = (const float*)d_in[6];
  const float* leb  = (const float*)d_in[7];
  const float* W    = (const float*)d_in[8];
  const float* bias = (const float*)d_in[9];
  const float* w1   = (const float*)d_in[10];
  const float* b1   = (const float*)d_in[11];
  const float* w2   = (const float*)d_in[12];
  const float* b2   = (const float*)d_in[13];
  float* out = (float*)d_out;
  float* ws  = (float*)d_ws;

  float* xn  = ws;                       // 131072 floats
  float* T1s = xn + 131072;              // 1572864 floats (frag-swizzled)
  float* T2  = T1s + 1572864;            // 1572864 floats
  short* Wb  = (short*)(T2 + 1572864);   // 98304 shorts
  short* w1b = Wb + 98304;               // 4096 shorts

  k_wb<<<50, 256, 0, stream>>>(W, w1, Wb, w1b);
  k_node_ln<<<512, 256, 0, stream>>>(x, mask, lng, lnb, xn);
  k_t12<<<256, 256, 0, stream>>>(xn, W, bias, T1s, T2);
  k_main<<<2048, 256, 0, stream>>>(A, mask, gu, leg, leb, b1, w2, b2,
                                   T1s, T2, Wb, w1b, out);
}

// Round 9
// 119.010 us; speedup vs baseline: 1.6958x; 1.0805x over previous
//
#include <hip/hip_runtime.h>
#include <hip/hip_bf16.h>
#include <math.h>

// EdgeSelector: B=32, N=64, D=64, H=4, E=256, HD=64
// out = [em (32,64,4,64) | sampled (32,64,4,64)] f32
// ws (floats): xn[131072] | T1s[1572864] (frag-swizzled) | T2[1572864] |
//              bf16: Wb[768*128] w1b[64*64]
// k_main: one block per (b, t-pair); 2 output tiles share Wc staging + B-frag reads.

typedef __attribute__((ext_vector_type(8))) short short8;   // 8 bf16 = 4 VGPR
typedef __attribute__((ext_vector_type(4))) short short4v;  // 4 bf16 = 8 B
typedef __attribute__((ext_vector_type(4))) float f32x4;

__device__ __forceinline__ short f2b(float f) {  // RNE via HW cvt (packs to cvt_pk)
  return (short)__builtin_bit_cast(unsigned short, __float2bfloat16(f));
}

#define WCS 136  // Wc row stride in shorts (272 B)
#define TS  72   // q/k/vT/A2/w row stride in shorts (144 B, 16B-aligned)

// LDS regions (bytes):
//  R0 [0,18432): Wc staging [64][136] during proj; after proj: Q_t0 @0, Q_t1 @9216
//                (then attn-w per tile, same spots)
//  RK [18432,36864): K_t0, K_t1; after scores barrier: A2_t0, A2_t1
//  RV [36864,55296): VT_t0, VT_t1
//  F  [55296,59904): 1152 f32
#define OFF_K0  18432
#define OFF_VT0 36864
#define OFF_F   55296
#define LDS_BYTES 59904
// sF: [0,192) T2h t0 | [192,384) T2h t1 | [384,448) mask t0 | [448,512) mask t1 |
//     [512,576) b1 | [576,640) w2 | [640,1152) logits (tile*4+h)*64

// ---------------- K1: xn = LN(x)*g+b, zeroed where row has no neighbors ----
__global__ __launch_bounds__(256) void k_node_ln(
    const float* __restrict__ x, const int* __restrict__ mask,
    const float* __restrict__ g, const float* __restrict__ bb,
    float* __restrict__ xn) {
  int tid = threadIdx.x;
  int row = blockIdx.x * 4 + (tid >> 6);
  int lane = tid & 63;
  float v = x[row * 64 + lane];
  float s = v;
#pragma unroll
  for (int m = 1; m < 64; m <<= 1) s += __shfl_xor(s, m, 64);
  float mean = s * (1.0f / 64.0f);
  float dv = v - mean;
  float s2 = dv * dv;
#pragma unroll
  for (int m = 1; m < 64; m <<= 1) s2 += __shfl_xor(s2, m, 64);
  float rstd = rsqrtf(s2 * (1.0f / 64.0f) + 1e-5f);
  float msum = (float)mask[row * 64 + lane];
#pragma unroll
  for (int m = 1; m < 64; m <<= 1) msum += __shfl_xor(msum, m, 64);
  float ped = (msum > 0.0f) ? 1.0f : 0.0f;
  xn[row * 64 + lane] = (dv * rstd * g[lane] + bb[lane]) * ped;
}

// ---- K2: T1s (frag-swizzled per part) ; T2[r,f] = W[f,64:128]·xn[r]+bias
// p<2 (swapped proj):  acc[nt][r] <-> (m = wave*16+lr,      d = nt*16+lh*4+r)
// p==2 (orig proj):    acc[nt][r] <-> (m = wave*16+lh*4+r,  d = nt*16+lr)
// T1s index: [((((b*3+p)*4+h)*4 + wave)*64 + lane)*16 + nt*4 + r]
__global__ __launch_bounds__(256) void k_t12(
    const float* __restrict__ xn, const float* __restrict__ W,
    const float* __restrict__ bias, float* __restrict__ T1s, float* __restrict__ T2) {
  __shared__ __align__(16) float sx[8 * 64];
  int tid = threadIdx.x;
  int r0 = blockIdx.x * 8;
#pragma unroll
  for (int u = 0; u < 2; ++u) {
    int idx = tid + 256 * u;
    sx[idx] = xn[r0 * 64 + idx];
  }
  __syncthreads();
#pragma unroll
  for (int ff = 0; ff < 3; ++ff) {
    int f = tid + 256 * ff;
    float acc1[8], acc2[8];
#pragma unroll
    for (int r = 0; r < 8; ++r) { acc1[r] = 0.f; acc2[r] = 0.f; }
    for (int e4 = 0; e4 < 64; e4 += 4) {
      float4 wa = *(const float4*)&W[f * 256 + e4];
      float4 wb = *(const float4*)&W[f * 256 + 64 + e4];
#pragma unroll
      for (int r = 0; r < 8; ++r) {
        float4 xv = *(const float4*)&sx[r * 64 + e4];
        acc1[r] += wa.x * xv.x + wa.y * xv.y + wa.z * xv.z + wa.w * xv.w;
        acc2[r] += wb.x * xv.x + wb.y * xv.y + wb.z * xv.z + wb.w * xv.w;
      }
    }
    float bv = bias[f];
    int p = f >> 8, hh = (f >> 6) & 3, dcol = f & 63;
#pragma unroll
    for (int r = 0; r < 8; ++r) {
      int m = r0 + r;
      int bb2 = m >> 6, mm = m & 63;
      int wv_ = mm >> 4;
      int lane, reg;
      if (p < 2) {
        lane = ((dcol >> 2) & 3) * 16 + (mm & 15);
        reg = (dcol >> 4) * 4 + (dcol & 3);
      } else {
        lane = ((mm >> 2) & 3) * 16 + (dcol & 15);
        reg = (dcol >> 4) * 4 + (mm & 3);
      }
      T1s[(size_t)((((bb2 * 3 + p) * 4 + hh) * 4 + wv_) * 64 + lane) * 16 + reg] =
          acc1[r];
      T2[m * 768 + f] = acc2[r] + bv;
    }
  }
}

// ---------------- K_wb: bf16 copies of W[:,128:256] and w1 ----------------
__global__ __launch_bounds__(256) void k_wb(const float* __restrict__ W,
                                            const float* __restrict__ w1,
                                            short* __restrict__ Wb,
                                            short* __restrict__ w1b) {
  int idx = blockIdx.x * 256 + threadIdx.x;
  if (idx < 12288) {  // 768 rows x 16 granules of 8
    int f = idx >> 4, gi = idx & 15;
    const float* src = &W[(size_t)f * 256 + 128 + gi * 8];
    short8 o;
#pragma unroll
    for (int i = 0; i < 8; ++i) o[i] = f2b(src[i]);
    *(short8*)&Wb[f * 128 + gi * 8] = o;
  } else if (idx < 12288 + 512) {  // 64 x 8 granules
    int g2 = idx - 12288;
    int f = g2 >> 3, gi = g2 & 7;
    const float* src = &w1[f * 64 + gi * 8];
    short8 o;
#pragma unroll
    for (int i = 0; i < 8; ++i) o[i] = f2b(src[i]);
    *(short8*)&w1b[f * 64 + gi * 8] = o;
  }
}

// ---------------- K3: fused per-(b, t-pair), 4 heads x 2 tiles ----------------
__global__ __launch_bounds__(256, 2) void k_main(
    const float* __restrict__ A, const int* __restrict__ mask,
    const float* __restrict__ gu, const float* __restrict__ leg,
    const float* __restrict__ leb, const float* __restrict__ b1g,
    const float* __restrict__ w2g, const float* __restrict__ b2g,
    const float* __restrict__ T1s, const float* __restrict__ T2,
    const short* __restrict__ Wb, const short* __restrict__ w1b,
    float* __restrict__ out) {
  __shared__ __align__(16) unsigned char smem[LDS_BYTES];
  short* sWc = (short*)smem;  // Wc staging during proj
  float* sF  = (float*)(smem + OFF_F);

  int tid = threadIdx.x;
  int bid0 = blockIdx.x;
  int wg = (bid0 & 7) * 128 + (bid0 >> 3);  // XCD swizzle (1024 % 8 == 0)
  int tq = wg & 31, b = wg >> 5;
  int t0 = tq * 2;
  int bt0 = b * 64 + t0;
  int wave = tid >> 6, lane = tid & 63, lr = lane & 15, lh = lane >> 4;

  // ---- stage block constants: masks (both tiles), b1, w2 ----
  if (tid < 64) sF[384 + tid] = (float)mask[bt0 * 64 + tid];
  else if (tid < 128) sF[448 + tid - 64] = (float)mask[(bt0 + 1) * 64 + tid - 64];
  else if (tid < 192) sF[512 + tid - 128] = b1g[tid - 128];
  else sF[576 + tid - 192] = w2g[tid - 192];

  // ---- An LN in registers for BOTH tiles: wave handles its 16 M-rows ----
  short8 af[2][4];
  {
    int m0 = wave * 16 + lr;
    float4 a4[2][8];
    float mean[2], rstd[2], mv[2];
#pragma unroll
    for (int e = 0; e < 2; ++e) {
      const float* Ar = A + ((size_t)((b * 64 + m0) * 64 + t0 + e)) * 128;
#pragma unroll
      for (int ks = 0; ks < 4; ++ks) {
        a4[e][2 * ks]     = *(const float4*)&Ar[ks * 32 + lh * 8];
        a4[e][2 * ks + 1] = *(const float4*)&Ar[ks * 32 + lh * 8 + 4];
      }
      float s = 0.f, s2 = 0.f;
#pragma unroll
      for (int q = 0; q < 8; ++q) {
        float4 u0 = a4[e][q];
        s += u0.x + u0.y + u0.z + u0.w;
        s2 += u0.x * u0.x + u0.y * u0.y + u0.z * u0.z + u0.w * u0.w;
      }
      s += __shfl_xor(s, 16, 64);  s += __shfl_xor(s, 32, 64);
      s2 += __shfl_xor(s2, 16, 64); s2 += __shfl_xor(s2, 32, 64);
      mean[e] = s * (1.0f / 128.0f);
      float var = s2 * (1.0f / 128.0f) - mean[e] * mean[e];
      rstd[e] = rsqrtf(var + 1e-5f);
      mv[e] = (float)mask[(bt0 + e) * 64 + m0];
    }
#pragma unroll
    for (int ks = 0; ks < 4; ++ks) {
      float4 g0 = *(const float4*)&leg[ks * 32 + lh * 8];
      float4 g1 = *(const float4*)&leg[ks * 32 + lh * 8 + 4];
      float4 c0 = *(const float4*)&leb[ks * 32 + lh * 8];
      float4 c1 = *(const float4*)&leb[ks * 32 + lh * 8 + 4];
      float gg[8] = {g0.x, g0.y, g0.z, g0.w, g1.x, g1.y, g1.z, g1.w};
      float cc[8] = {c0.x, c0.y, c0.z, c0.w, c1.x, c1.y, c1.z, c1.w};
#pragma unroll
      for (int e = 0; e < 2; ++e) {
        float4 u0 = a4[e][2 * ks], u1 = a4[e][2 * ks + 1];
        float vv[8] = {u0.x, u0.y, u0.z, u0.w, u1.x, u1.y, u1.z, u1.w};
#pragma unroll
        for (int i = 0; i < 8; ++i)
          af[e][ks][i] = f2b(((vv[i] - mean[e]) * rstd[e] * gg[i] + cc[i]) * mv[e]);
      }
    }
  }

#pragma unroll 1
  for (int h = 0; h < 4; ++h) {
    __syncthreads();  // fence: prior head's tail LDS reads done before R0 overwrite
    // stage both tiles' T2h (visible at next barrier)
    if (tid < 192) sF[tid] = T2[bt0 * 768 + (tid >> 6) * 256 + h * 64 + (tid & 63)];
    if (tid >= 64) {
      int i2 = tid - 64;
      sF[192 + i2] = T2[(bt0 + 1) * 768 + (i2 >> 6) * 256 + h * 64 + (i2 & 63)];
    }

    // ---- projection, part order K(p=1), V(p=2), Q(p=0 last, lands in R0) ----
#pragma unroll
    for (int pp = 0; pp < 3; ++pp) {
      const int p = (pp + 1) % 3;  // 1, 2, 0
      const int Fbase = p * 256 + h * 64;
      // stage Wc (pure bf16 copy, coalesced 16B granules), shared by both tiles
#pragma unroll
      for (int u = 0; u < 4; ++u) {
        int idx = tid + 256 * u;
        int dR = idx >> 4, gi = idx & 15;
        *(short8*)&sWc[dR * WCS + gi * 8] =
            *(const short8*)&Wb[(size_t)(Fbase + dR) * 128 + gi * 8];
      }
      // T1 fragment preload — t-independent, inits BOTH tiles' accumulators
      float4 t1f[4];
#pragma unroll
      for (int nt = 0; nt < 4; ++nt)
        t1f[nt] = *(const float4*)&T1s[
            (size_t)((((b * 3 + p) * 4 + h) * 4 + wave) * 64 + lane) * 16 + nt * 4];
      __syncthreads();  // staging (and T2h on pp=0) visible
      f32x4 acc0[4], acc1[4];
#pragma unroll
      for (int nt = 0; nt < 4; ++nt) {
        acc0[nt][0] = t1f[nt].x; acc0[nt][1] = t1f[nt].y;
        acc0[nt][2] = t1f[nt].z; acc0[nt][3] = t1f[nt].w;
        acc1[nt] = acc0[nt];
      }
      if (p == 2) {
        // orig orientation: acc[nt][r] = qkv[m=wave*16+lh*4+r][d=nt*16+lr]
#pragma unroll
        for (int ks = 0; ks < 4; ++ks)
#pragma unroll
          for (int nt = 0; nt < 4; ++nt) {
            short8 bf = *(const short8*)&sWc[(nt * 16 + lr) * WCS + ks * 32 + lh * 8];
            acc0[nt] = __builtin_amdgcn_mfma_f32_16x16x32_bf16(af[0][ks], bf, acc0[nt], 0, 0, 0);
            acc1[nt] = __builtin_amdgcn_mfma_f32_16x16x32_bf16(af[1][ks], bf, acc1[nt], 0, 0, 0);
          }
      } else {
        // swapped: acc[nt][r] = qkv[m=wave*16+lr][d=nt*16+lh*4+r]
#pragma unroll
        for (int ks = 0; ks < 4; ++ks)
#pragma unroll
          for (int nt = 0; nt < 4; ++nt) {
            short8 bf = *(const short8*)&sWc[(nt * 16 + lr) * WCS + ks * 32 + lh * 8];
            acc0[nt] = __builtin_amdgcn_mfma_f32_16x16x32_bf16(bf, af[0][ks], acc0[nt], 0, 0, 0);
            acc1[nt] = __builtin_amdgcn_mfma_f32_16x16x32_bf16(bf, af[1][ks], acc1[nt], 0, 0, 0);
          }
      }
      if (p == 0) __syncthreads();  // Q: all Wc reads drained before R0 overwrite
#pragma unroll
      for (int e = 0; e < 2; ++e) {
        const f32x4* acc = (e == 0) ? acc0 : acc1;
        if (p == 2) {
          short* sVTt = (short*)(smem + OFF_VT0 + e * 9216);
#pragma unroll
          for (int nt = 0; nt < 4; ++nt) {
            float t2v = sF[e * 192 + 128 + nt * 16 + lr];
            short4v vp;
#pragma unroll
            for (int r = 0; r < 4; ++r) vp[r] = f2b(acc[nt][r] + t2v);
            *(short4v*)&sVTt[(nt * 16 + lr) * TS + wave * 16 + lh * 4] = vp;
          }
        } else {
          float scale = (p == 0) ? 0.125f : 1.0f;  // hd^-0.5 on q
          short* dst = (p == 0) ? (short*)(smem + e * 9216)
                                : (short*)(smem + OFF_K0 + e * 9216);
#pragma unroll
          for (int nt = 0; nt < 4; ++nt) {
            float4 t24 = *(const float4*)&sF[e * 192 + p * 64 + nt * 16 + lh * 4];
            float tv[4] = {t24.x, t24.y, t24.z, t24.w};
            short4v qp;
#pragma unroll
            for (int r = 0; r < 4; ++r) qp[r] = f2b((acc[nt][r] + tv[r]) * scale);
            *(short4v*)&dst[(wave * 16 + lr) * TS + nt * 16 + lh * 4] = qp;
          }
        }
      }
      if (p != 0) __syncthreads();  // K/V visible; Wc reads done before next stage
    }

    // ---- tail, phase 1: scores + masked softmax + w-write, per tile ----
#pragma unroll
    for (int e = 0; e < 2; ++e) {
      short* sQt = (short*)(smem + e * 9216);
      short* sKt = (short*)(smem + OFF_K0 + e * 9216);
      f32x4 sc[4] = {};
#pragma unroll
      for (int ks = 0; ks < 2; ++ks) {
        short8 qf = *(const short8*)&sQt[(wave * 16 + lr) * TS + ks * 32 + lh * 8];
#pragma unroll
        for (int nt = 0; nt < 4; ++nt) {
          short8 kf = *(const short8*)&sKt[(nt * 16 + lr) * TS + ks * 32 + lh * 8];
          sc[nt] = __builtin_amdgcn_mfma_f32_16x16x32_bf16(kf, qf, sc[nt], 0, 0, 0);
        }
      }
      // softmax over k (per-lane 16 values + 2 shuffles across lh groups)
      float mj = sF[384 + e * 64 + wave * 16 + lr];
      float mx = sc[0][0];
#pragma unroll
      for (int nt = 0; nt < 4; ++nt)
#pragma unroll
        for (int r = 0; r < 4; ++r) mx = fmaxf(mx, sc[nt][r]);
      mx = fmaxf(mx, __shfl_xor(mx, 16, 64));
      mx = fmaxf(mx, __shfl_xor(mx, 32, 64));
      float pv[4][4], mkv[4][4], Zf = 0.f, S = 0.f;
#pragma unroll
      for (int nt = 0; nt < 4; ++nt) {
        float4 mk4 = *(const float4*)&sF[384 + e * 64 + nt * 16 + lh * 4];
        float mk[4] = {mk4.x, mk4.y, mk4.z, mk4.w};
#pragma unroll
        for (int r = 0; r < 4; ++r) {
          float ev = __expf(sc[nt][r] - mx);
          pv[nt][r] = ev;
          mkv[nt][r] = mk[r];
          Zf += ev;
          S += ev * mk[r];
        }
      }
      Zf += __shfl_xor(Zf, 16, 64); Zf += __shfl_xor(Zf, 32, 64);
      S  += __shfl_xor(S, 16, 64);  S  += __shfl_xor(S, 32, 64);
      // w = softmax*m3 renormed == p*mk*mj / (mj*S + 1e-10*Z)
      float inv = mj / (S + 1e-10f * Zf);
#pragma unroll
      for (int nt = 0; nt < 4; ++nt) {
        short4v wp;
#pragma unroll
        for (int r = 0; r < 4; ++r) wp[r] = f2b(pv[nt][r] * mkv[nt][r] * inv);
        *(short4v*)&sQt[(wave * 16 + lr) * TS + nt * 16 + lh * 4] = wp;
      }
    }
    __syncthreads();  // all kf reads done before A2 overwrites the K region

    // ---- tail, phase 2: A2 + hmid + logits, per tile ----
#pragma unroll
    for (int e = 0; e < 2; ++e) {
      short* sWtt = (short*)(smem + e * 9216);
      short* sVTt = (short*)(smem + OFF_VT0 + e * 9216);
      short* sA2t = (short*)(smem + OFF_K0 + e * 9216);
      f32x4 a2[4] = {};
#pragma unroll
      for (int ks = 0; ks < 2; ++ks) {
        short8 wf = *(const short8*)&sWtt[(wave * 16 + lr) * TS + ks * 32 + lh * 8];
#pragma unroll
        for (int nt = 0; nt < 4; ++nt) {
          short8 vf = *(const short8*)&sVTt[(nt * 16 + lr) * TS + ks * 32 + lh * 8];
          a2[nt] = __builtin_amdgcn_mfma_f32_16x16x32_bf16(vf, wf, a2[nt], 0, 0, 0);
        }
      }
      // A2 row-major [j][d], packed b64 (same-wave rows)
#pragma unroll
      for (int nt = 0; nt < 4; ++nt) {
        short4v ap;
#pragma unroll
        for (int r = 0; r < 4; ++r) ap[r] = f2b(a2[nt][r]);
        *(short4v*)&sA2t[(wave * 16 + lr) * TS + nt * 16 + lh * 4] = ap;
      }
      // hmid (transposed): hm[nt][r] = hmid[o=nt*16+lh*4+r][j=wave*16+lr]
      f32x4 hm[4] = {};
#pragma unroll
      for (int ks = 0; ks < 2; ++ks) {
        short8 a2f = *(const short8*)&sA2t[(wave * 16 + lr) * TS + ks * 32 + lh * 8];
#pragma unroll
        for (int nt = 0; nt < 4; ++nt) {
          short8 wf = *(const short8*)&w1b[(nt * 16 + lr) * 64 + ks * 32 + lh * 8];
          hm[nt] = __builtin_amdgcn_mfma_f32_16x16x32_bf16(wf, a2f, hm[nt], 0, 0, 0);
        }
      }
      float pp_ = 0.f;
#pragma unroll
      for (int nt = 0; nt < 4; ++nt) {
        float4 b14 = *(const float4*)&sF[512 + nt * 16 + lh * 4];
        float4 w24 = *(const float4*)&sF[576 + nt * 16 + lh * 4];
        float bb4[4] = {b14.x, b14.y, b14.z, b14.w};
        float ww4[4] = {w24.x, w24.y, w24.z, w24.w};
#pragma unroll
        for (int r = 0; r < 4; ++r)
          pp_ += fmaxf(hm[nt][r] + bb4[r], 0.f) * ww4[r];
      }
      pp_ += __shfl_xor(pp_, 16, 64);
      pp_ += __shfl_xor(pp_, 32, 64);
      if (lh == 0) sF[640 + (e * 4 + h) * 64 + wave * 16 + lr] = pp_;
    }
  }
  __syncthreads();  // all logits visible

  // ---- parallel tails: wave handles head=wave for both tiles ----
#pragma unroll
  for (int it = 0; it < 2; ++it) {
    int tile = it, hh = wave, j = lane;
    int btx = bt0 + tile;
    float l = sF[640 + (tile * 4 + hh) * 64 + j] + b2g[0];
    float mjv = sF[384 + tile * 64 + j];
    float mx = l;
#pragma unroll
    for (int mm = 1; mm < 64; mm <<= 1) mx = fmaxf(mx, __shfl_xor(mx, mm, 64));
    float pv = __expf(l - mx);
    float Z = pv;
#pragma unroll
    for (int mm = 1; mm < 64; mm <<= 1) Z += __shfl_xor(Z, mm, 64);
    float ep = (pv / Z) * mjv;
    float S = ep;
#pragma unroll
    for (int mm = 1; mm < 64; mm <<= 1) S += __shfl_xor(S, mm, 64);
    float em = ep / (S + 1e-10f);
    float u = gu[((size_t)btx * 4 + hh) * 64 + j];
    float gg = -__logf(-__logf(u + 1e-10f) + 1e-10f);
    float l2 = __logf(em + 1e-10f) + gg;  // TAU = 1
    float mx2 = l2;
#pragma unroll
    for (int mm = 1; mm < 64; mm <<= 1) mx2 = fmaxf(mx2, __shfl_xor(mx2, mm, 64));
    float p2 = __expf(l2 - mx2);
    float Z2 = p2;
#pragma unroll
    for (int mm = 1; mm < 64; mm <<= 1) Z2 += __shfl_xor(Z2, mm, 64);
    float smp = p2 / Z2;
    size_t o = ((size_t)btx * 4 + hh) * 64 + j;
    out[o] = em;
    out[524288 + o] = smp;
  }
}

extern "C" void kernel_launch(void* const* d_in, const int* in_sizes, int n_in,
                              void* d_out, int out_size, void* d_ws, size_t ws_size,
                              hipStream_t stream) {
  const float* x    = (const float*)d_in[0];
  const float* A    = (const float*)d_in[1];
  const int*   mask = (const int*)d_in[2];
  const float* gu   = (const float*)d_in[3];
  const float* lng  = (const float*)d_in[4];
  const float* lnb  = (const float*)d_in[5];
  const float* leg  = (const float*)d_in[6];
  const float* leb  = (const float*)d_in[7];
  const float* W    = (const float*)d_in[8];
  const float* bias = (const float*)d_in[9];
  const float* w1   = (const float*)d_in[10];
  const float* b1   = (const float*)d_in[11];
  const float* w2   = (const float*)d_in[12];
  const float* b2   = (const float*)d_in[13];
  float* out = (float*)d_out;
  float* ws  = (float*)d_ws;

  float* xn  = ws;                       // 131072 floats
  float* T1s = xn + 131072;              // 1572864 floats (frag-swizzled)
  float* T2  = T1s + 1572864;            // 1572864 floats
  short* Wb  = (short*)(T2 + 1572864);   // 98304 shorts
  short* w1b = Wb + 98304;               // 4096 shorts

  k_wb<<<50, 256, 0, stream>>>(W, w1, Wb, w1b);
  k_node_ln<<<512, 256, 0, stream>>>(x, mask, lng, lnb, xn);
  k_t12<<<256, 256, 0, stream>>>(xn, W, bias, T1s, T2);
  k_main<<<1024, 256, 0, stream>>>(A, mask, gu, leg, leb, b1, w2, b2,
                                   T1s, T2, Wb, w1b, out);
}